// Round 15
// baseline (288.018 us; speedup 1.0000x reference)
//
#include <hip/hip_runtime.h>
#include <hip/hip_bf16.h>
#include <math.h>

typedef unsigned short u16;   // bf16 storage
typedef __attribute__((ext_vector_type(8))) short s8v;    // 8 bf16 = 4 VGPR
typedef __attribute__((ext_vector_type(4))) float f4v;    // MFMA acc

#define B_    8
#define C_    64
#define HW_   4096
#define NPIX  32768     // B_*HW_
#define DI    128
#define NCH   256
#define CHL   16        // HW_/NCH

__device__ __forceinline__ float b2f(u16 v){ return __uint_as_float(((unsigned)v)<<16); }
__device__ __forceinline__ u16 f2b(float x){
  unsigned u = __float_as_uint(x);
  u += 0x7fff + ((u >> 16) & 1);      // RTNE
  return (u16)(u >> 16);
}
__device__ __forceinline__ float gelu_exact(float x){ return 0.5f*x*(1.0f+erff(x*0.70710678118654752f)); }
__device__ __forceinline__ float leaky02(float x){ return x>0.f ? x : 0.2f*x; }
__device__ __forceinline__ float softplus_(float x){ return fmaxf(x,0.f)+log1pf(__expf(-fabsf(x))); }
__device__ __forceinline__ float silu_(float x){ return x / (1.0f + __expf(-x)); }
__device__ __forceinline__ void unpack16(uint4 q0, uint4 q1, float* v){
  unsigned w[8]={q0.x,q0.y,q0.z,q0.w,q1.x,q1.y,q1.z,q1.w};
  #pragma unroll
  for(int j=0;j<8;j++){
    v[2*j]   = __uint_as_float(w[j]<<16);
    v[2*j+1] = __uint_as_float(w[j]&0xffff0000u);
  }
}

// ====== prep: all weights -> bf16 transposed [COUT][CIN]; W2 fused (xproj/dtw) ======
__global__ void k_prep(const float* __restrict__ vin_w1, const float* __restrict__ vin_w2,
                       const float* __restrict__ ssm_in_w, const float* __restrict__ xproj,
                       const float* __restrict__ dtw, const float* __restrict__ ssm_outw,
                       const float* __restrict__ ff_w1, const float* __restrict__ ff_w2,
                       u16* __restrict__ wv1, u16* __restrict__ wv2, u16* __restrict__ wsi,
                       u16* __restrict__ wdb, u16* __restrict__ wout, u16* __restrict__ wf1,
                       u16* __restrict__ wf2t){
  int g = blockIdx.x*256 + threadIdx.x;     // 80*256 = 20480
  if(g < 4096){
    int n=g>>6, c=g&63;
    wv1[n*64+c]=f2b(vin_w1[c*64+n]);
    wv2[n*64+c]=f2b(vin_w2[c*64+n]);
  }
  if(g < 16384){
    int n=g>>6, c=g&63;
    wsi[n*64+c]=f2b(ssm_in_w[c*256+n]);
    wf1[n*64+c]=f2b(ff_w1[c*256+n]);
    int n2=g/256, k2=g%256;
    wf2t[n2*256+k2]=f2b(ff_w2[k2*64+n2]);
  }
  if(g < 8192){
    int n=g>>7, k=g&127;
    wout[n*128+k]=f2b(ssm_outw[k*64+n]);
  }
  if(g < 20480){
    int n=g/128, k=g%128;
    float v;
    if(n < 128){
      v = 0.f;
      for(int r=0;r<4;r++) v += xproj[k*36+r]*dtw[r*128+n];
    }else{
      v = xproj[k*36+4+(n-128)];
    }
    wdb[n*128+k]=f2b(v);
  }
}

// ====== fused: NCHW fp32 -> (xT bf16 NHWC) + LayerNorm + vin_w1 MFMA -> outp ======
__global__ __launch_bounds__(256) void k_trans_ln_mm(const float* __restrict__ x,
                     const float* __restrict__ g, const float* __restrict__ bta,
                     const u16* __restrict__ wT,
                     u16* __restrict__ xT, u16* __restrict__ outp){
  const int LDA = 72, NS = 4;
  __shared__ float tile[64][65];
  __shared__ __align__(16) u16 sA[64*LDA];
  __shared__ __align__(16) u16 sW[64*LDA];
  int tid = threadIdx.x;
  int blk = blockIdx.x;            // 512
  int b = blk >> 6;
  int hwb = (blk & 63) << 6;
  int lane = tid & 63, row = tid >> 6;
  const float* src = x + (size_t)b*C_*HW_;
  #pragma unroll
  for(int k=0;k<16;k++){
    int c = row + 4*k;
    tile[c][lane] = src[c*HW_ + hwb + lane];
  }
  for(int idx=tid; idx<64*8; idx+=256){
    int n = idx>>3, c8 = (idx&7)*8;
    *(uint4*)(sW + n*LDA + c8) = *(const uint4*)(wT + n*64 + c8);
  }
  __syncthreads();
  u16* dstT = xT + (size_t)b*HW_*C_;
  #pragma unroll
  for(int k=0;k<16;k++){
    int hwl = row + 4*k;
    dstT[(hwb+hwl)*C_ + lane] = f2b(tile[lane][hwl]);
  }
  float gg = g[lane], bb = bta[lane];
  #pragma unroll
  for(int i=0;i<16;i++){
    int hwl = row*16 + i;
    float v = tile[lane][hwl];
    float s = v, sq = v*v;
    #pragma unroll
    for(int o=32;o>0;o>>=1){ s += __shfl_xor(s,o); sq += __shfl_xor(sq,o); }
    float m = s*(1.f/64.f);
    float var = sq*(1.f/64.f) - m*m;
    float r = rsqrtf(var + 1e-5f);
    sA[hwl*LDA + lane] = f2b((v-m)*r*gg + bb);
  }
  __syncthreads();
  int ln = tid & 63, wv = tid >> 6;
  int mrow = ln & 15, quad = ln >> 4;
  f4v acc[NS];
  #pragma unroll
  for(int i=0;i<NS;i++) acc[i] = (f4v){0.f,0.f,0.f,0.f};
  const u16* aBase = sA + (wv*16 + mrow)*LDA + quad*8;
  const u16* wBase = sW + mrow*LDA + quad*8;
  #pragma unroll
  for(int kk=0; kk<64; kk+=32){
    s8v af = *(const s8v*)(aBase + kk);
    #pragma unroll
    for(int ns=0; ns<NS; ns++){
      s8v bf = *(const s8v*)(wBase + ns*16*LDA + kk);
      acc[ns] = __builtin_amdgcn_mfma_f32_16x16x32_bf16(af, bf, acc[ns], 0, 0, 0);
    }
  }
  int p0 = blk*64;
  int pr = p0 + wv*16 + quad*4;
  #pragma unroll
  for(int ns=0; ns<NS; ns++){
    int n = ns*16 + mrow;
    #pragma unroll
    for(int r=0;r<4;r++)
      outp[(size_t)(pr+r)*64 + n] = f2b(acc[ns][r]);
  }
}

// ========== generic MFMA matmul: [NPIX,CIN](bf16) @ wT[COUT][CIN](bf16) ==========
template<int CIN, int COUT, int ACT, bool OUTF32>
__global__ __launch_bounds__(256) void k_mfma(const u16* __restrict__ wT,
                     const u16* __restrict__ in, const float* __restrict__ bias,
                     const u16* __restrict__ res, void* __restrict__ outv){
  const int KCH = (CIN < 128) ? CIN : 128;
  const int LDA = KCH + 8;
  const int NS  = COUT / 16;
  __shared__ __align__(16) u16 sA[64*LDA];
  __shared__ __align__(16) u16 sW[COUT*LDA];
  int tid = threadIdx.x;
  int p0 = blockIdx.x * 64;
  int ln = tid & 63, wv = tid >> 6;
  int mrow = ln & 15, quad = ln >> 4;
  f4v acc[NS];
  #pragma unroll
  for(int i=0;i<NS;i++) acc[i] = (f4v){0.f,0.f,0.f,0.f};
  const u16* aBase = sA + (wv*16 + mrow)*LDA + quad*8;
  const u16* wBase = sW + mrow*LDA + quad*8;
  const int RW = KCH/8;
  for(int k0=0; k0<CIN; k0+=KCH){
    if(k0) __syncthreads();
    for(int idx=tid; idx<COUT*RW; idx+=256){
      int n = idx/RW, c8 = (idx%RW)*8;
      *(uint4*)(sW + n*LDA + c8) = *(const uint4*)(wT + (size_t)n*CIN + k0 + c8);
    }
    for(int g=tid; g<64*RW; g+=256){
      int row = g / RW, c8 = (g % RW)*8;
      *(uint4*)(sA + row*LDA + c8) = *(const uint4*)(in + (size_t)(p0+row)*CIN + k0 + c8);
    }
    __syncthreads();
    #pragma unroll
    for(int kk=0; kk<KCH; kk+=32){
      s8v af = *(const s8v*)(aBase + kk);
      #pragma unroll
      for(int ns=0; ns<NS; ns++){
        s8v bf = *(const s8v*)(wBase + ns*16*LDA + kk);
        acc[ns] = __builtin_amdgcn_mfma_f32_16x16x32_bf16(af, bf, acc[ns], 0, 0, 0);
      }
    }
  }
  int pr = p0 + wv*16 + quad*4;
  #pragma unroll
  for(int ns=0; ns<NS; ns++){
    int n = ns*16 + mrow;
    float bs = bias ? bias[n] : 0.f;
    #pragma unroll
    for(int r=0;r<4;r++){
      float v = acc[ns][r] + bs;
      if(ACT==1) v = leaky02(v);
      else if(ACT==2) v = softplus_(v);
      if(res) v += b2f(res[(size_t)(pr+r)*COUT + n]);
      if(OUTF32) ((float*)outv)[(size_t)(pr+r)*COUT + n] = v;
      else       ((u16*)outv)[(size_t)(pr+r)*COUT + n] = f2b(v);
    }
  }
}

// ====== fused: ssm_in matmul (64->256) + causal dwconv1d(k=4) + silu; no xz ======
__global__ __launch_bounds__(256) void k_mfma_ssm(const u16* __restrict__ wT,
                     const u16* __restrict__ x0,
                     const float* __restrict__ cw, const float* __restrict__ cb,
                     u16* __restrict__ xi, u16* __restrict__ zs){
  const int CIN=64, COUT=256, LDA=72, NS=16;
  __shared__ __align__(16) u16 sA[64*LDA];
  __shared__ __align__(16) u16 sW[COUT*LDA];
  __shared__ __align__(16) u16 ubuf[67*128];
  int tid = threadIdx.x;
  int p0 = blockIdx.x*64;
  int ln = tid & 63, wv = tid >> 6;
  int mrow = ln & 15, quad = ln >> 4;
  for(int idx=tid; idx<COUT*8; idx+=256){
    int n = idx>>3, c8 = (idx&7)*8;
    *(uint4*)(sW + n*LDA + c8) = *(const uint4*)(wT + n*64 + c8);
  }
  for(int g=tid; g<64*8; g+=256){
    int row = g >> 3, c8 = (g & 7)*8;
    *(uint4*)(sA + row*LDA + c8) = *(const uint4*)(x0 + (size_t)(p0+row)*64 + c8);
  }
  __syncthreads();
  f4v acc[NS];
  #pragma unroll
  for(int i=0;i<NS;i++) acc[i] = (f4v){0.f,0.f,0.f,0.f};
  const u16* aBase = sA + (wv*16 + mrow)*LDA + quad*8;
  const u16* wBase = sW + mrow*LDA + quad*8;
  #pragma unroll
  for(int kk=0; kk<CIN; kk+=32){
    s8v af = *(const s8v*)(aBase + kk);
    #pragma unroll
    for(int ns=0; ns<NS; ns++){
      s8v bf = *(const s8v*)(wBase + ns*16*LDA + kk);
      acc[ns] = __builtin_amdgcn_mfma_f32_16x16x32_bf16(af, bf, acc[ns], 0, 0, 0);
    }
  }
  bool bstart = ((p0 & 4095) == 0);
  for(int idx=tid; idx<384; idx+=256){
    int j = idx >> 7, n = idx & 127;
    float a2 = 0.f;
    if(!bstart){
      const u16* xr = x0 + (size_t)(p0-3+j)*64;
      #pragma unroll 8
      for(int c=0;c<64;c++) a2 += b2f(xr[c]) * b2f(sW[n*LDA+c]);
    }
    ubuf[j*128 + n] = f2b(a2);
  }
  int prl = wv*16 + quad*4;
  #pragma unroll
  for(int ns=0; ns<NS; ns++){
    int n = ns*16 + mrow;
    if(n < 128){
      #pragma unroll
      for(int r=0;r<4;r++) ubuf[(prl+r+3)*128 + n] = f2b(acc[ns][r]);
    }else{
      #pragma unroll
      for(int r=0;r<4;r++) zs[(size_t)(p0+prl+r)*128 + (n-128)] = f2b(silu_(acc[ns][r]));
    }
  }
  __syncthreads();
  int d4 = tid & 31;
  float4 cbv = *(const float4*)(cb + d4*4);
  for(int row = tid >> 5; row < 64; row += 8){
    float a0=cbv.x, a1=cbv.y, a2=cbv.z, a3=cbv.w;
    #pragma unroll
    for(int k=0;k<4;k++){
      ushort4 v = *(const ushort4*)(ubuf + (row+k)*128 + d4*4);
      float4 wv4 = *(const float4*)(cw + k*128 + d4*4);
      a0 += b2f(v.x)*wv4.x; a1 += b2f(v.y)*wv4.y;
      a2 += b2f(v.z)*wv4.z; a3 += b2f(v.w)*wv4.w;
    }
    ushort4 o; o.x=f2b(silu_(a0)); o.y=f2b(silu_(a1)); o.z=f2b(silu_(a2)); o.w=f2b(silu_(a3));
    *(ushort4*)(xi + (size_t)(p0+row)*128 + d4*4) = o;
  }
}

// ====== pure dt/bc MFMA: 1024 blocks x 128 thr, 32 pixels/block, stream A+W per K-chunk ======
__global__ __launch_bounds__(128) void k_dtbc(const u16* __restrict__ wT,
                     const u16* __restrict__ in, const float* __restrict__ dtbias,
                     u16* __restrict__ dtout, u16* __restrict__ bcout){
  const int COUT=160, LDW=72, LDA=72, NS=10;
  __shared__ __align__(16) u16 sA[32*LDA];     // 4.6 KB (per-chunk 32x64)
  __shared__ __align__(16) u16 sW[COUT*LDW];   // 23 KB (per-chunk 160x64)
  int tid = threadIdx.x;
  int p0 = blockIdx.x * 32;
  int ln = tid & 63, wv = tid >> 6;            // 2 waves
  int mrow = ln & 15, quad = ln >> 4;
  f4v acc[NS];
  #pragma unroll
  for(int i=0;i<NS;i++) acc[i] = (f4v){0.f,0.f,0.f,0.f};
  #pragma unroll
  for(int k0=0; k0<128; k0+=64){
    if(k0) __syncthreads();
    for(int idx=tid; idx<COUT*8; idx+=128){
      int n = idx>>3, c8 = (idx&7)*8;
      *(uint4*)(sW + n*LDW + c8) = *(const uint4*)(wT + n*128 + k0 + c8);
    }
    for(int g=tid; g<32*8; g+=128){
      int row = g >> 3, c8 = (g & 7)*8;
      *(uint4*)(sA + row*LDA + c8) = *(const uint4*)(in + (size_t)(p0+row)*128 + k0 + c8);
    }
    __syncthreads();
    #pragma unroll
    for(int kk=0; kk<64; kk+=32){
      s8v af = *(const s8v*)(sA + (wv*16+mrow)*LDA + kk + quad*8);
      #pragma unroll
      for(int ns=0; ns<NS; ns++){
        s8v bf = *(const s8v*)(sW + (ns*16+mrow)*LDW + kk + quad*8);
        acc[ns] = __builtin_amdgcn_mfma_f32_16x16x32_bf16(af, bf, acc[ns], 0, 0, 0);
      }
    }
  }
  int pr = p0 + wv*16 + quad*4;
  #pragma unroll
  for(int ns=0; ns<NS; ns++){
    int n = ns*16 + mrow;
    if(n < 128){
      float bs = dtbias[n];
      #pragma unroll
      for(int r=0;r<4;r++)
        dtout[(size_t)(pr+r)*128 + n] = f2b(softplus_(acc[ns][r] + bs));
    }else{
      #pragma unroll
      for(int r=0;r<4;r++)
        bcout[(size_t)(pr+r)*32 + (n-128)] = f2b(acc[ns][r]);
    }
  }
}

// ====== scan phase 1: LDS-free, 1 chunk/thread ======
__global__ __launch_bounds__(256) void k_scan1(const u16* __restrict__ dt, const u16* __restrict__ xi,
                        const u16* __restrict__ bc, const float* __restrict__ alog,
                        u16* __restrict__ Pb, u16* __restrict__ Qb){
  int t = blockIdx.x*256 + threadIdx.x;    // 1024 blocks
  int d = t & 127;
  int ch = (t >> 7) & 255;
  int b = t >> 15;
  int pbase = b*HW_ + ch*CHL;
  float A[16];
  #pragma unroll
  for(int s=0;s<16;s++) A[s] = -__expf(alog[d*16+s]);
  float dtv[16], uv[16];
  #pragma unroll
  for(int i=0;i<CHL;i++){
    dtv[i] = b2f(dt[(size_t)(pbase+i)*128 + d]);
    uv[i]  = dtv[i] * b2f(xi[(size_t)(pbase+i)*128 + d]);
  }
  float Q[16], sumdt = 0.f;
  #pragma unroll
  for(int s=0;s<16;s++) Q[s] = 0.f;
  #pragma unroll
  for(int i=0;i<CHL;i++){
    float Bv[16];
    unpack16(*(const uint4*)(bc + (size_t)(pbase+i)*32),
             *(const uint4*)(bc + (size_t)(pbase+i)*32 + 8), Bv);
    sumdt += dtv[i];
    #pragma unroll
    for(int s=0;s<16;s++){
      float a = __expf(dtv[i]*A[s]);
      Q[s] = a*Q[s] + uv[i]*Bv[s];
    }
  }
  int gidx = ch*16384 + (b*128+d)*16;
  unsigned pw[8], qw[8];
  #pragma unroll
  for(int j=0;j<8;j++){
    pw[j] = (unsigned)f2b(__expf(A[2*j]*sumdt)) | ((unsigned)f2b(__expf(A[2*j+1]*sumdt))<<16);
    qw[j] = (unsigned)f2b(Q[2*j]) | ((unsigned)f2b(Q[2*j+1])<<16);
  }
  *(uint4*)(Pb+gidx)   = make_uint4(pw[0],pw[1],pw[2],pw[3]);
  *(uint4*)(Pb+gidx+8) = make_uint4(pw[4],pw[5],pw[6],pw[7]);
  *(uint4*)(Qb+gidx)   = make_uint4(qw[0],qw[1],qw[2],qw[3]);
  *(uint4*)(Qb+gidx+8) = make_uint4(qw[4],qw[5],qw[6],qw[7]);
}

// ---------------- scan phase 2 (2 sequences per thread) ----------------
__global__ void k_scan2(const u16* __restrict__ Pb, const u16* __restrict__ Qb,
                        u16* __restrict__ Hin){
  int g2 = (blockIdx.x*64 + threadIdx.x)*2;
  float h0 = 0.f, h1 = 0.f;
  #pragma unroll 8
  for(int ch=0; ch<NCH; ch++){
    unsigned p = *(const unsigned*)(Pb + ch*16384 + g2);
    unsigned q = *(const unsigned*)(Qb + ch*16384 + g2);
    *(unsigned*)(Hin + ch*16384 + g2) = (unsigned)f2b(h0) | ((unsigned)f2b(h1)<<16);
    h0 = __uint_as_float(p<<16)*h0 + __uint_as_float(q<<16);
    h1 = __uint_as_float(p&0xffff0000u)*h1 + __uint_as_float(q&0xffff0000u);
  }
}

// ------- scan phase 3: 1024 blocks x 256 thr, 2 chunks/block + out-proj MFMA -------
__global__ __launch_bounds__(256) void k_scan3_mm(const u16* __restrict__ dt, const u16* __restrict__ xi,
                        const u16* __restrict__ bc, const u16* __restrict__ zs,
                        const float* __restrict__ alog, const float* __restrict__ Dp,
                        const u16* __restrict__ Hin, const u16* __restrict__ wout,
                        const u16* __restrict__ x0, u16* __restrict__ y){
  const int LDY = 136, LDW = 136;
  int blk = blockIdx.x;            // 1024: b = blk>>7, chpair = blk&127
  int b = blk >> 7;
  int tid = threadIdx.x;
  int half = tid >> 7;             // 0/1: which chunk of the pair
  int d = tid & 127;
  int ch = (blk & 127)*2 + half;
  __shared__ __align__(16) u16 sY[2*CHL*LDY];    // 8.7 KB
  __shared__ __align__(16) u16 sWo[64*LDW];      // 17.4 KB (shared by both halves)
  __shared__ __align__(16) u16 sbc[2*CHL*32];    // 2 KB
  for(int idx=tid; idx<64*16; idx+=256){
    int n = idx>>4, c8 = (idx&15)*8;
    *(uint4*)(sWo + n*LDW + c8) = *(const uint4*)(wout + n*128 + c8);
  }
  int pbase = b*HW_ + ch*CHL;
  if(d < 64) ((uint4*)(sbc + half*CHL*32))[d] = ((const uint4*)(bc + (size_t)pbase*32))[d];
  float A[16], h[16];
  u16 hbuf[16];
  int gidx = ch*16384 + (b*128+d)*16;
  *(uint4*)hbuf     = *(const uint4*)(Hin+gidx);
  *(uint4*)(hbuf+8) = *(const uint4*)(Hin+gidx+8);
  #pragma unroll
  for(int s=0;s<16;s++){ A[s] = -__expf(alog[d*16+s]); h[s] = b2f(hbuf[s]); }
  float Dd = Dp[d];
  float dtv[16], xiv[16], zsv[16];
  #pragma unroll
  for(int i=0;i<CHL;i++){
    dtv[i] = b2f(dt[(size_t)(pbase+i)*128 + d]);
    xiv[i] = b2f(xi[(size_t)(pbase+i)*128 + d]);
    zsv[i] = b2f(zs[(size_t)(pbase+i)*128 + d]);
  }
  __syncthreads();
  const u16* mybc = sbc + half*CHL*32;
  u16* myY = sY + half*CHL*LDY;
  #pragma unroll
  for(int i=0;i<CHL;i++){
    float Bv[16], Cv[16];
    unpack16(*(const uint4*)(mybc + i*32),      *(const uint4*)(mybc + i*32 + 8),  Bv);
    unpack16(*(const uint4*)(mybc + i*32 + 16), *(const uint4*)(mybc + i*32 + 24), Cv);
    float u = dtv[i]*xiv[i];
    float acc = Dd*xiv[i];
    #pragma unroll
    for(int s=0;s<16;s++){
      float a = __expf(dtv[i]*A[s]);
      h[s] = a*h[s] + u*Bv[s];
      acc += h[s]*Cv[s];
    }
    myY[i*LDY + d] = f2b(acc * zsv[i]);
  }
  __syncthreads();
  // out-projection per half: yss[16][128] @ wout^T -> y[16][64] (+ x0)
  int ln = tid & 63, wv = (tid >> 6) & 1;    // 2 waves per half
  int mrow = ln & 15, quad = ln >> 4;
  f4v acc2[2];
  acc2[0] = (f4v){0.f,0.f,0.f,0.f};
  acc2[1] = (f4v){0.f,0.f,0.f,0.f};
  #pragma unroll
  for(int kk=0; kk<128; kk+=32){
    s8v af = *(const s8v*)(myY + mrow*LDY + kk + quad*8);
    #pragma unroll
    for(int ns=0; ns<2; ns++){
      int n0 = wv*32 + ns*16;
      s8v bf = *(const s8v*)(sWo + (n0+mrow)*LDW + kk + quad*8);
      acc2[ns] = __builtin_amdgcn_mfma_f32_16x16x32_bf16(af, bf, acc2[ns], 0, 0, 0);
    }
  }
  #pragma unroll
  for(int ns=0; ns<2; ns++){
    int n = wv*32 + ns*16 + mrow;
    #pragma unroll
    for(int r=0;r<4;r++){
      int px = pbase + quad*4 + r;
      y[(size_t)px*64 + n] = f2b(acc2[ns][r] + b2f(x0[(size_t)px*64 + n]));
    }
  }
}

// ========== MFMA with fused LayerNorm on A (CIN=64) ==========
template<int COUT, int ACT>
__global__ __launch_bounds__(256) void k_mfma_ln(const u16* __restrict__ wT,
                     const u16* __restrict__ in, const float* __restrict__ g,
                     const float* __restrict__ bta, u16* __restrict__ outp){
  const int CIN = 64, LDA = 72, NS = COUT/16;
  __shared__ __align__(16) u16 sA[64*LDA];
  __shared__ __align__(16) u16 sW[COUT*LDA];
  int tid = threadIdx.x;
  int p0 = blockIdx.x * 64;
  int ln = tid & 63, wv = tid >> 6;
  int mrow = ln & 15, quad = ln >> 4;
  for(int idx=tid; idx<COUT*8; idx+=256){
    int n = idx>>3, c8 = (idx&7)*8;
    *(uint4*)(sW + n*LDA + c8) = *(const uint4*)(wT + n*64 + c8);
  }
  float gg = g[ln], bb = bta[ln];
  #pragma unroll
  for(int i=0;i<16;i++){
    int row = wv*16 + i;
    float v = b2f(in[(size_t)(p0+row)*64 + ln]);
    float s = v, sq = v*v;
    #pragma unroll
    for(int o=32;o>0;o>>=1){ s += __shfl_xor(s,o); sq += __shfl_xor(sq,o); }
    float m = s*(1.f/64.f);
    float var = sq*(1.f/64.f) - m*m;
    float r = rsqrtf(var + 1e-5f);
    sA[row*LDA + ln] = f2b((v-m)*r*gg + bb);
  }
  __syncthreads();
  f4v acc[NS];
  #pragma unroll
  for(int i=0;i<NS;i++) acc[i] = (f4v){0.f,0.f,0.f,0.f};
  const u16* aBase = sA + (wv*16 + mrow)*LDA + quad*8;
  const u16* wBase = sW + mrow*LDA + quad*8;
  #pragma unroll
  for(int kk=0; kk<CIN; kk+=32){
    s8v af = *(const s8v*)(aBase + kk);
    #pragma unroll
    for(int ns=0; ns<NS; ns++){
      s8v bf = *(const s8v*)(wBase + ns*16*LDA + kk);
      acc[ns] = __builtin_amdgcn_mfma_f32_16x16x32_bf16(af, bf, acc[ns], 0, 0, 0);
    }
  }
  int pr = p0 + wv*16 + quad*4;
  #pragma unroll
  for(int ns=0; ns<NS; ns++){
    int n = ns*16 + mrow;
    #pragma unroll
    for(int r=0;r<4;r++){
      float v = acc[ns][r];
      if(ACT==1) v = leaky02(v);
      outp[(size_t)(pr+r)*COUT + n] = f2b(v);
    }
  }
}

// ========== final MFMA: [NPIX,256] @ wf2t[64][256] + res, fp32 NCHW store ==========
__global__ __launch_bounds__(256) void k_mfma_fin(const u16* __restrict__ wT,
                     const u16* __restrict__ in, const u16* __restrict__ res,
                     float* __restrict__ outp){
  const int CIN=256, COUT=64, KCH=128, LDA=136, NS=4;
  __shared__ __align__(16) u16 sA[64*LDA];
  __shared__ __align__(16) u16 sW[COUT*LDA];
  int tid = threadIdx.x;
  int p0 = blockIdx.x * 64;
  int ln = tid & 63, wv = tid >> 6;
  int mrow = ln & 15, quad = ln >> 4;
  f4v acc[NS];
  #pragma unroll
  for(int i=0;i<NS;i++) acc[i] = (f4v){0.f,0.f,0.f,0.f};
  const u16* aBase = sA + (wv*16 + mrow)*LDA + quad*8;
  const u16* wBase = sW + mrow*LDA + quad*8;
  for(int k0=0; k0<CIN; k0+=KCH){
    if(k0) __syncthreads();
    for(int idx=tid; idx<COUT*16; idx+=256){
      int n = idx>>4, c8 = (idx&15)*8;
      *(uint4*)(sW + n*LDA + c8) = *(const uint4*)(wT + n*256 + k0 + c8);
    }
    for(int g=tid; g<64*16; g+=256){
      int row = g >> 4, c8 = (g & 15)*8;
      *(uint4*)(sA + row*LDA + c8) = *(const uint4*)(in + (size_t)(p0+row)*CIN + k0 + c8);
    }
    __syncthreads();
    #pragma unroll
    for(int kk=0; kk<KCH; kk+=32){
      s8v af = *(const s8v*)(aBase + kk);
      #pragma unroll
      for(int ns=0; ns<NS; ns++){
        s8v bf = *(const s8v*)(wBase + ns*16*LDA + kk);
        acc[ns] = __builtin_amdgcn_mfma_f32_16x16x32_bf16(af, bf, acc[ns], 0, 0, 0);
      }
    }
  }
  int pr = p0 + wv*16 + quad*4;
  int b = blockIdx.x >> 6;
  int hwr = ((blockIdx.x & 63) << 6) + wv*16 + quad*4;
  #pragma unroll
  for(int ns=0; ns<NS; ns++){
    int n = ns*16 + mrow;
    float4 v4;
    v4.x = acc[ns][0] + b2f(res[(size_t)(pr+0)*64 + n]);
    v4.y = acc[ns][1] + b2f(res[(size_t)(pr+1)*64 + n]);
    v4.z = acc[ns][2] + b2f(res[(size_t)(pr+2)*64 + n]);
    v4.w = acc[ns][3] + b2f(res[(size_t)(pr+3)*64 + n]);
    *(float4*)(outp + (size_t)b*C_*HW_ + (size_t)n*HW_ + hwr) = v4;
  }
}

// ---------------- depthwise 3x3 SAME, 4 channels per thread ----------------
template<int CN, int ACT>
__global__ void k_dw3(const u16* __restrict__ in, const float* __restrict__ wgt,
                      const u16* __restrict__ res1, const u16* __restrict__ res2,
                      u16* __restrict__ out){
  const int C4 = CN/4;
  int g = blockIdx.x*256 + threadIdx.x;
  int c4 = g % C4;
  int pix = g / C4;
  int w = pix & 63;
  int h = (pix >> 6) & 63;
  int b = pix >> 12;
  float a0=0.f, a1=0.f, a2=0.f, a3=0.f;
  #pragma unroll
  for(int kh=0;kh<3;kh++){
    int hh = h + kh - 1;
    if((unsigned)hh < 64u){
      #pragma unroll
      for(int kw=0;kw<3;kw++){
        int ww = w + kw - 1;
        if((unsigned)ww < 64u){
          ushort4 v = *(const ushort4*)(in + (size_t)((b*64+hh)*64 + ww)*CN + c4*4);
          float4 wv = *(const float4*)(wgt + (kh*3+kw)*CN + c4*4);
          a0 += b2f(v.x)*wv.x; a1 += b2f(v.y)*wv.y;
          a2 += b2f(v.z)*wv.z; a3 += b2f(v.w)*wv.w;
        }
      }
    }
  }
  if(ACT==1){ a0=leaky02(a0); a1=leaky02(a1); a2=leaky02(a2); a3=leaky02(a3); }
  else if(ACT==2){ a0=gelu_exact(a0); a1=gelu_exact(a1); a2=gelu_exact(a2); a3=gelu_exact(a3); }
  size_t ob = (size_t)pix*CN + c4*4;
  if(res1){ ushort4 r = *(const ushort4*)(res1 + ob);
            a0+=b2f(r.x); a1+=b2f(r.y); a2+=b2f(r.z); a3+=b2f(r.w); }
  if(res2){ ushort4 r = *(const ushort4*)(res2 + ob);
            a0+=b2f(r.x); a1+=b2f(r.y); a2+=b2f(r.z); a3+=b2f(r.w); }
  ushort4 o; o.x=f2b(a0); o.y=f2b(a1); o.z=f2b(a2); o.w=f2b(a3);
  *(ushort4*)(out + ob) = o;
}

extern "C" void kernel_launch(void* const* d_in, const int* in_sizes, int n_in,
                              void* d_out, int out_size, void* d_ws, size_t ws_size,
                              hipStream_t stream) {
  const float* x        = (const float*)d_in[0];
  const float* ln1_g    = (const float*)d_in[1];
  const float* ln1_b    = (const float*)d_in[2];
  const float* vin_w1   = (const float*)d_in[3];
  const float* vin_dw   = (const float*)d_in[4];
  const float* vin_w2   = (const float*)d_in[5];
  const float* vout_dw1 = (const float*)d_in[6];
  const float* vout_dw2 = (const float*)d_in[7];
  const float* ssm_in_w = (const float*)d_in[8];
  const float* ssm_cw   = (const float*)d_in[9];
  const float* ssm_cb   = (const float*)d_in[10];
  const float* ssm_xprj = (const float*)d_in[11];
  const float* ssm_dtw  = (const float*)d_in[12];
  const float* ssm_dtb  = (const float*)d_in[13];
  const float* ssm_Alog = (const float*)d_in[14];
  const float* ssm_D    = (const float*)d_in[15];
  const float* ssm_outw = (const float*)d_in[16];
  const float* ln2_g    = (const float*)d_in[17];
  const float* ln2_b    = (const float*)d_in[18];
  const float* ff_w1    = (const float*)d_in[19];
  const float* ff_dw    = (const float*)d_in[20];
  const float* ff_w2    = (const float*)d_in[21];
  float* out = (float*)d_out;

  // ---- bf16 arena, lifetime-packed (units: bf16 elements) ----
  const size_t M = 1u<<20;
  u16* U   = (u16*)d_ws;
  u16* xT  = U;              // [0,2M)
  u16* tA  = U + 2*M;        // [2M,4M)   Hin during scan
  u16* tB  = U + 4*M;        // [4M,6M)
  u16* x0  = U + 6*M;        // [6M,8M)   x0, later xR
  u16* xi  = U + 8*M;        // [8M,12M)
  u16* zs  = U + 12*M;       // [12M,16M)
  u16* xz  = U + 16*M;       // [16M,24M) Pb/Qb; y; t1
  u16* dtb = U + 24*M;       // [24M,28M) dt; t2
  u16* bc  = U + 28*M;       // [28M,29M)
  u16* Pb  = U + 16*M;       // [16M,20M)
  u16* Qb  = U + 20*M;       // [20M,24M)
  u16* Hin = tA;             // [2M,6M)
  u16* y   = U + 16*M;       // [16M,18M)
  u16* t2  = dtb;            // [24M,32M)
  // pre-transposed bf16 weights:
  u16* wv1  = U + 33*M;
  u16* wv2  = wv1 + 4096;
  u16* wsi  = wv2 + 4096;
  u16* wdb  = wsi + 16384;
  u16* wout = wdb + 20480;
  u16* wf1  = wout + 8192;
  u16* wf2t = wf1 + 16384;

  k_prep<<<80,256,0,stream>>>(vin_w1, vin_w2, ssm_in_w, ssm_xprj, ssm_dtw, ssm_outw,
                              ff_w1, ff_w2, wv1, wv2, wsi, wdb, wout, wf1, wf2t);

  // --- vision in path ---
  k_trans_ln_mm<<<512,256,0,stream>>>(x, ln1_g, ln1_b, wv1, xT, tB);
  k_dw3<64,2><<<2048,256,0,stream>>>(tB, vin_dw, nullptr, nullptr, tA);
  k_mfma<64,64,0,false><<<512,256,0,stream>>>(wv2, tA, nullptr, nullptr, x0);

  // --- SSM ---
  k_mfma_ssm<<<512,256,0,stream>>>(wsi, x0, ssm_cw, ssm_cb, xi, zs);
  k_dtbc<<<1024,128,0,stream>>>(wdb, xi, ssm_dtb, dtb, bc);
  k_scan1<<<1024,256,0,stream>>>(dtb, xi, bc, ssm_Alog, Pb, Qb);
  k_scan2<<<128,64,0,stream>>>(Pb, Qb, Hin);
  k_scan3_mm<<<1024,256,0,stream>>>(dtb, xi, bc, zs, ssm_Alog, ssm_D, Hin, wout, x0, y);

  // --- vision out path:  xR = dw2(gelu(dw1(y))) + y + xT ---
  k_dw3<64,2><<<2048,256,0,stream>>>(y, vout_dw1, nullptr, nullptr, tA);
  k_dw3<64,0><<<2048,256,0,stream>>>(tA, vout_dw2, y, xT, x0);   // x0 now = xR

  // --- FFN ---
  k_mfma_ln<256,1><<<512,256,0,stream>>>(wf1, x0, ln2_g, ln2_b, xz);  // t1
  k_dw3<256,1><<<8192,256,0,stream>>>(xz, ff_dw, nullptr, nullptr, t2);
  k_mfma_fin<<<512,256,0,stream>>>(wf2t, t2, x0, out);
}

// Round 16
// 281.478 us; speedup vs baseline: 1.0232x; 1.0232x over previous
//
#include <hip/hip_runtime.h>
#include <hip/hip_bf16.h>
#include <math.h>

typedef unsigned short u16;   // bf16 storage
typedef __attribute__((ext_vector_type(8))) short s8v;    // 8 bf16 = 4 VGPR
typedef __attribute__((ext_vector_type(4))) float f4v;    // MFMA acc

#define B_    8
#define C_    64
#define HW_   4096
#define NPIX  32768     // B_*HW_
#define DI    128
#define NCH   256
#define CHL   16        // HW_/NCH

__device__ __forceinline__ float b2f(u16 v){ return __uint_as_float(((unsigned)v)<<16); }
__device__ __forceinline__ u16 f2b(float x){
  unsigned u = __float_as_uint(x);
  u += 0x7fff + ((u >> 16) & 1);      // RTNE
  return (u16)(u >> 16);
}
__device__ __forceinline__ float gelu_exact(float x){ return 0.5f*x*(1.0f+erff(x*0.70710678118654752f)); }
__device__ __forceinline__ float leaky02(float x){ return x>0.f ? x : 0.2f*x; }
__device__ __forceinline__ float softplus_(float x){ return fmaxf(x,0.f)+log1pf(__expf(-fabsf(x))); }
__device__ __forceinline__ float silu_(float x){ return x / (1.0f + __expf(-x)); }
__device__ __forceinline__ void unpack16(uint4 q0, uint4 q1, float* v){
  unsigned w[8]={q0.x,q0.y,q0.z,q0.w,q1.x,q1.y,q1.z,q1.w};
  #pragma unroll
  for(int j=0;j<8;j++){
    v[2*j]   = __uint_as_float(w[j]<<16);
    v[2*j+1] = __uint_as_float(w[j]&0xffff0000u);
  }
}

// ====== prep: all weights -> bf16 transposed [COUT][CIN]; W2 fused (xproj/dtw) ======
__global__ void k_prep(const float* __restrict__ vin_w1, const float* __restrict__ vin_w2,
                       const float* __restrict__ ssm_in_w, const float* __restrict__ xproj,
                       const float* __restrict__ dtw, const float* __restrict__ ssm_outw,
                       const float* __restrict__ ff_w1, const float* __restrict__ ff_w2,
                       u16* __restrict__ wv1, u16* __restrict__ wv2, u16* __restrict__ wsi,
                       u16* __restrict__ wdb, u16* __restrict__ wout, u16* __restrict__ wf1,
                       u16* __restrict__ wf2t){
  int g = blockIdx.x*256 + threadIdx.x;     // 80*256 = 20480
  if(g < 4096){
    int n=g>>6, c=g&63;
    wv1[n*64+c]=f2b(vin_w1[c*64+n]);
    wv2[n*64+c]=f2b(vin_w2[c*64+n]);
  }
  if(g < 16384){
    int n=g>>6, c=g&63;
    wsi[n*64+c]=f2b(ssm_in_w[c*256+n]);
    wf1[n*64+c]=f2b(ff_w1[c*256+n]);
    int n2=g/256, k2=g%256;
    wf2t[n2*256+k2]=f2b(ff_w2[k2*64+n2]);
  }
  if(g < 8192){
    int n=g>>7, k=g&127;
    wout[n*128+k]=f2b(ssm_outw[k*64+n]);
  }
  if(g < 20480){
    int n=g/128, k=g%128;
    float v;
    if(n < 128){
      v = 0.f;
      for(int r=0;r<4;r++) v += xproj[k*36+r]*dtw[r*128+n];
    }else{
      v = xproj[k*36+4+(n-128)];
    }
    wdb[n*128+k]=f2b(v);
  }
}

// ====== fused: NCHW fp32 -> (xT bf16 NHWC) + LayerNorm + vin_w1 MFMA -> outp ======
__global__ __launch_bounds__(256) void k_trans_ln_mm(const float* __restrict__ x,
                     const float* __restrict__ g, const float* __restrict__ bta,
                     const u16* __restrict__ wT,
                     u16* __restrict__ xT, u16* __restrict__ outp){
  const int LDA = 72, NS = 4;
  __shared__ float tile[64][65];
  __shared__ __align__(16) u16 sA[64*LDA];
  __shared__ __align__(16) u16 sW[64*LDA];
  int tid = threadIdx.x;
  int blk = blockIdx.x;            // 512
  int b = blk >> 6;
  int hwb = (blk & 63) << 6;
  int lane = tid & 63, row = tid >> 6;
  const float* src = x + (size_t)b*C_*HW_;
  #pragma unroll
  for(int k=0;k<16;k++){
    int c = row + 4*k;
    tile[c][lane] = src[c*HW_ + hwb + lane];
  }
  for(int idx=tid; idx<64*8; idx+=256){
    int n = idx>>3, c8 = (idx&7)*8;
    *(uint4*)(sW + n*LDA + c8) = *(const uint4*)(wT + n*64 + c8);
  }
  __syncthreads();
  u16* dstT = xT + (size_t)b*HW_*C_;
  #pragma unroll
  for(int k=0;k<16;k++){
    int hwl = row + 4*k;
    dstT[(hwb+hwl)*C_ + lane] = f2b(tile[lane][hwl]);
  }
  float gg = g[lane], bb = bta[lane];
  #pragma unroll
  for(int i=0;i<16;i++){
    int hwl = row*16 + i;
    float v = tile[lane][hwl];
    float s = v, sq = v*v;
    #pragma unroll
    for(int o=32;o>0;o>>=1){ s += __shfl_xor(s,o); sq += __shfl_xor(sq,o); }
    float m = s*(1.f/64.f);
    float var = sq*(1.f/64.f) - m*m;
    float r = rsqrtf(var + 1e-5f);
    sA[hwl*LDA + lane] = f2b((v-m)*r*gg + bb);
  }
  __syncthreads();
  int ln = tid & 63, wv = tid >> 6;
  int mrow = ln & 15, quad = ln >> 4;
  f4v acc[NS];
  #pragma unroll
  for(int i=0;i<NS;i++) acc[i] = (f4v){0.f,0.f,0.f,0.f};
  const u16* aBase = sA + (wv*16 + mrow)*LDA + quad*8;
  const u16* wBase = sW + mrow*LDA + quad*8;
  #pragma unroll
  for(int kk=0; kk<64; kk+=32){
    s8v af = *(const s8v*)(aBase + kk);
    #pragma unroll
    for(int ns=0; ns<NS; ns++){
      s8v bf = *(const s8v*)(wBase + ns*16*LDA + kk);
      acc[ns] = __builtin_amdgcn_mfma_f32_16x16x32_bf16(af, bf, acc[ns], 0, 0, 0);
    }
  }
  int p0 = blk*64;
  int pr = p0 + wv*16 + quad*4;
  #pragma unroll
  for(int ns=0; ns<NS; ns++){
    int n = ns*16 + mrow;
    #pragma unroll
    for(int r=0;r<4;r++)
      outp[(size_t)(pr+r)*64 + n] = f2b(acc[ns][r]);
  }
}

// ========== generic MFMA matmul: [NPIX,CIN](bf16) @ wT[COUT][CIN](bf16) ==========
template<int CIN, int COUT, int ACT, bool OUTF32>
__global__ __launch_bounds__(256) void k_mfma(const u16* __restrict__ wT,
                     const u16* __restrict__ in, const float* __restrict__ bias,
                     const u16* __restrict__ res, void* __restrict__ outv){
  const int KCH = (CIN < 128) ? CIN : 128;
  const int LDA = KCH + 8;
  const int NS  = COUT / 16;
  __shared__ __align__(16) u16 sA[64*LDA];
  __shared__ __align__(16) u16 sW[COUT*LDA];
  int tid = threadIdx.x;
  int p0 = blockIdx.x * 64;
  int ln = tid & 63, wv = tid >> 6;
  int mrow = ln & 15, quad = ln >> 4;
  f4v acc[NS];
  #pragma unroll
  for(int i=0;i<NS;i++) acc[i] = (f4v){0.f,0.f,0.f,0.f};
  const u16* aBase = sA + (wv*16 + mrow)*LDA + quad*8;
  const u16* wBase = sW + mrow*LDA + quad*8;
  const int RW = KCH/8;
  for(int k0=0; k0<CIN; k0+=KCH){
    if(k0) __syncthreads();
    for(int idx=tid; idx<COUT*RW; idx+=256){
      int n = idx/RW, c8 = (idx%RW)*8;
      *(uint4*)(sW + n*LDA + c8) = *(const uint4*)(wT + (size_t)n*CIN + k0 + c8);
    }
    for(int g=tid; g<64*RW; g+=256){
      int row = g / RW, c8 = (g % RW)*8;
      *(uint4*)(sA + row*LDA + c8) = *(const uint4*)(in + (size_t)(p0+row)*CIN + k0 + c8);
    }
    __syncthreads();
    #pragma unroll
    for(int kk=0; kk<KCH; kk+=32){
      s8v af = *(const s8v*)(aBase + kk);
      #pragma unroll
      for(int ns=0; ns<NS; ns++){
        s8v bf = *(const s8v*)(wBase + ns*16*LDA + kk);
        acc[ns] = __builtin_amdgcn_mfma_f32_16x16x32_bf16(af, bf, acc[ns], 0, 0, 0);
      }
    }
  }
  int pr = p0 + wv*16 + quad*4;
  #pragma unroll
  for(int ns=0; ns<NS; ns++){
    int n = ns*16 + mrow;
    float bs = bias ? bias[n] : 0.f;
    #pragma unroll
    for(int r=0;r<4;r++){
      float v = acc[ns][r] + bs;
      if(ACT==1) v = leaky02(v);
      else if(ACT==2) v = softplus_(v);
      if(res) v += b2f(res[(size_t)(pr+r)*COUT + n]);
      if(OUTF32) ((float*)outv)[(size_t)(pr+r)*COUT + n] = v;
      else       ((u16*)outv)[(size_t)(pr+r)*COUT + n] = f2b(v);
    }
  }
}

// ====== fused: ssm_in matmul + causal conv + silu + dt/bc MFMA (xi tile stays in LDS) ======
__global__ __launch_bounds__(256) void k_ssm_dtbc(const u16* __restrict__ wT,
                     const u16* __restrict__ x0,
                     const float* __restrict__ cw, const float* __restrict__ cb,
                     const u16* __restrict__ wdb, const float* __restrict__ dtbias,
                     u16* __restrict__ xi, u16* __restrict__ zs,
                     u16* __restrict__ dtout, u16* __restrict__ bcout){
  const int LDA=72, NS=16, LDY=136, LDWD=136, NS2=10;
  // flat LDS 63.2 KB, phase-aliased:
  //   P1: sW[0,18432) sA[18432,23040) ubuf[23040,31616)
  //   P2 (conv): xiT[0,8704) over dead sW head; ubuf still live
  //   P3 (dtbc): wdbS[8704,30464) over dead sW tail+sA+ubuf
  __shared__ __align__(16) u16 S[31616];
  u16* sW   = S;
  u16* sA   = S + 18432;
  u16* ubuf = S + 23040;
  u16* xiT  = S;
  u16* wdbS = S + 8704;
  int tid = threadIdx.x;
  int p0 = blockIdx.x*64;
  int ln = tid & 63, wv = tid >> 6;
  int mrow = ln & 15, quad = ln >> 4;
  for(int idx=tid; idx<256*8; idx+=256){
    int n = idx>>3, c8 = (idx&7)*8;
    *(uint4*)(sW + n*LDA + c8) = *(const uint4*)(wT + n*64 + c8);
  }
  for(int g=tid; g<64*8; g+=256){
    int row = g >> 3, c8 = (g & 7)*8;
    *(uint4*)(sA + row*LDA + c8) = *(const uint4*)(x0 + (size_t)(p0+row)*64 + c8);
  }
  __syncthreads();
  f4v acc[NS];
  #pragma unroll
  for(int i=0;i<NS;i++) acc[i] = (f4v){0.f,0.f,0.f,0.f};
  const u16* aBase = sA + (wv*16 + mrow)*LDA + quad*8;
  const u16* wBase = sW + mrow*LDA + quad*8;
  #pragma unroll
  for(int kk=0; kk<64; kk+=32){
    s8v af = *(const s8v*)(aBase + kk);
    #pragma unroll
    for(int ns=0; ns<NS; ns++){
      s8v bf = *(const s8v*)(wBase + ns*16*LDA + kk);
      acc[ns] = __builtin_amdgcn_mfma_f32_16x16x32_bf16(af, bf, acc[ns], 0, 0, 0);
    }
  }
  // 3 halo rows of u (VALU dot vs sW); zero at batch starts
  bool bstart = ((p0 & 4095) == 0);
  for(int idx=tid; idx<384; idx+=256){
    int j = idx >> 7, n = idx & 127;
    float a2 = 0.f;
    if(!bstart){
      const u16* xr = x0 + (size_t)(p0-3+j)*64;
      #pragma unroll 8
      for(int c=0;c<64;c++) a2 += b2f(xr[c]) * b2f(sW[n*LDA+c]);
    }
    ubuf[j*128 + n] = f2b(a2);
  }
  int prl = wv*16 + quad*4;
  #pragma unroll
  for(int ns=0; ns<NS; ns++){
    int n = ns*16 + mrow;
    if(n < 128){
      #pragma unroll
      for(int r=0;r<4;r++) ubuf[(prl+r+3)*128 + n] = f2b(acc[ns][r]);
    }else{
      #pragma unroll
      for(int r=0;r<4;r++) zs[(size_t)(p0+prl+r)*128 + (n-128)] = f2b(silu_(acc[ns][r]));
    }
  }
  __syncthreads();   // ubuf complete; sW/sA now dead
  // causal conv + silu -> xi (global) + xiT (LDS, A-layout)
  int d4 = tid & 31;
  float4 cbv = *(const float4*)(cb + d4*4);
  for(int row = tid >> 5; row < 64; row += 8){
    float a0=cbv.x, a1=cbv.y, a2=cbv.z, a3=cbv.w;
    #pragma unroll
    for(int k=0;k<4;k++){
      ushort4 v = *(const ushort4*)(ubuf + (row+k)*128 + d4*4);
      float4 wv4 = *(const float4*)(cw + k*128 + d4*4);
      a0 += b2f(v.x)*wv4.x; a1 += b2f(v.y)*wv4.y;
      a2 += b2f(v.z)*wv4.z; a3 += b2f(v.w)*wv4.w;
    }
    ushort4 o; o.x=f2b(silu_(a0)); o.y=f2b(silu_(a1)); o.z=f2b(silu_(a2)); o.w=f2b(silu_(a3));
    *(ushort4*)(xi + (size_t)(p0+row)*128 + d4*4) = o;
    *(ushort4*)(xiT + row*LDY + d4*4) = o;
  }
  __syncthreads();   // ubuf dead; xiT complete
  // stage wdb [160][128] -> wdbS
  for(int idx=tid; idx<160*16; idx+=256){
    int n = idx>>4, c8 = (idx&15)*8;
    *(uint4*)(wdbS + n*LDWD + c8) = *(const uint4*)(wdb + n*128 + c8);
  }
  __syncthreads();
  // dtbc MFMA: xiT[64][128] @ wdbS[160][128]^T
  f4v acc2[NS2];
  #pragma unroll
  for(int i=0;i<NS2;i++) acc2[i] = (f4v){0.f,0.f,0.f,0.f};
  #pragma unroll
  for(int kk=0; kk<128; kk+=32){
    s8v af = *(const s8v*)(xiT + (wv*16+mrow)*LDY + kk + quad*8);
    #pragma unroll
    for(int ns=0; ns<NS2; ns++){
      s8v bf = *(const s8v*)(wdbS + (ns*16+mrow)*LDWD + kk + quad*8);
      acc2[ns] = __builtin_amdgcn_mfma_f32_16x16x32_bf16(af, bf, acc2[ns], 0, 0, 0);
    }
  }
  int pr = p0 + wv*16 + quad*4;
  #pragma unroll
  for(int ns=0; ns<NS2; ns++){
    int n = ns*16 + mrow;
    if(n < 128){
      float bs = dtbias[n];
      #pragma unroll
      for(int r=0;r<4;r++)
        dtout[(size_t)(pr+r)*128 + n] = f2b(softplus_(acc2[ns][r] + bs));
    }else{
      #pragma unroll
      for(int r=0;r<4;r++)
        bcout[(size_t)(pr+r)*32 + (n-128)] = f2b(acc2[ns][r]);
    }
  }
}

// ====== scan phase 1: LDS-free, 1 chunk/thread ======
__global__ __launch_bounds__(256) void k_scan1(const u16* __restrict__ dt, const u16* __restrict__ xi,
                        const u16* __restrict__ bc, const float* __restrict__ alog,
                        u16* __restrict__ Pb, u16* __restrict__ Qb){
  int t = blockIdx.x*256 + threadIdx.x;    // 1024 blocks
  int d = t & 127;
  int ch = (t >> 7) & 255;
  int b = t >> 15;
  int pbase = b*HW_ + ch*CHL;
  float A[16];
  #pragma unroll
  for(int s=0;s<16;s++) A[s] = -__expf(alog[d*16+s]);
  float dtv[16], uv[16];
  #pragma unroll
  for(int i=0;i<CHL;i++){
    dtv[i] = b2f(dt[(size_t)(pbase+i)*128 + d]);
    uv[i]  = dtv[i] * b2f(xi[(size_t)(pbase+i)*128 + d]);
  }
  float Q[16], sumdt = 0.f;
  #pragma unroll
  for(int s=0;s<16;s++) Q[s] = 0.f;
  #pragma unroll
  for(int i=0;i<CHL;i++){
    float Bv[16];
    unpack16(*(const uint4*)(bc + (size_t)(pbase+i)*32),
             *(const uint4*)(bc + (size_t)(pbase+i)*32 + 8), Bv);
    sumdt += dtv[i];
    #pragma unroll
    for(int s=0;s<16;s++){
      float a = __expf(dtv[i]*A[s]);
      Q[s] = a*Q[s] + uv[i]*Bv[s];
    }
  }
  int gidx = ch*16384 + (b*128+d)*16;
  unsigned pw[8], qw[8];
  #pragma unroll
  for(int j=0;j<8;j++){
    pw[j] = (unsigned)f2b(__expf(A[2*j]*sumdt)) | ((unsigned)f2b(__expf(A[2*j+1]*sumdt))<<16);
    qw[j] = (unsigned)f2b(Q[2*j]) | ((unsigned)f2b(Q[2*j+1])<<16);
  }
  *(uint4*)(Pb+gidx)   = make_uint4(pw[0],pw[1],pw[2],pw[3]);
  *(uint4*)(Pb+gidx+8) = make_uint4(pw[4],pw[5],pw[6],pw[7]);
  *(uint4*)(Qb+gidx)   = make_uint4(qw[0],qw[1],qw[2],qw[3]);
  *(uint4*)(Qb+gidx+8) = make_uint4(qw[4],qw[5],qw[6],qw[7]);
}

// ---------------- scan phase 2 (2 sequences per thread) ----------------
__global__ void k_scan2(const u16* __restrict__ Pb, const u16* __restrict__ Qb,
                        u16* __restrict__ Hin){
  int g2 = (blockIdx.x*64 + threadIdx.x)*2;
  float h0 = 0.f, h1 = 0.f;
  #pragma unroll 8
  for(int ch=0; ch<NCH; ch++){
    unsigned p = *(const unsigned*)(Pb + ch*16384 + g2);
    unsigned q = *(const unsigned*)(Qb + ch*16384 + g2);
    *(unsigned*)(Hin + ch*16384 + g2) = (unsigned)f2b(h0) | ((unsigned)f2b(h1)<<16);
    h0 = __uint_as_float(p<<16)*h0 + __uint_as_float(q<<16);
    h1 = __uint_as_float(p&0xffff0000u)*h1 + __uint_as_float(q&0xffff0000u);
  }
}

// ------- scan phase 3 (global column loads) + out-proj MFMA (R14 config) -------
__global__ __launch_bounds__(128) void k_scan3_mm(const u16* __restrict__ dt, const u16* __restrict__ xi,
                        const u16* __restrict__ bc, const u16* __restrict__ zs,
                        const float* __restrict__ alog, const float* __restrict__ Dp,
                        const u16* __restrict__ Hin, const u16* __restrict__ wout,
                        const u16* __restrict__ x0, u16* __restrict__ y){
  const int LDY = 136, LDW = 136;
  int blk = blockIdx.x;
  int ch = blk & (NCH-1);
  int b = blk >> 8;
  int d = threadIdx.x, tid = threadIdx.x;
  __shared__ __align__(16) u16 sY[CHL*LDY];
  __shared__ __align__(16) u16 sWo[64*LDW];
  __shared__ __align__(16) u16 sbc[CHL*32];
  for(int idx=tid; idx<64*16; idx+=128){
    int n = idx>>4, c8 = (idx&15)*8;
    *(uint4*)(sWo + n*LDW + c8) = *(const uint4*)(wout + n*128 + c8);
  }
  int pbase = b*HW_ + ch*CHL;
  if(tid < 64) ((uint4*)sbc)[tid] = ((const uint4*)(bc + (size_t)pbase*32))[tid];
  float A[16], h[16];
  u16 hbuf[16];
  int gidx = ch*16384 + (b*128+d)*16;
  *(uint4*)hbuf     = *(const uint4*)(Hin+gidx);
  *(uint4*)(hbuf+8) = *(const uint4*)(Hin+gidx+8);
  #pragma unroll
  for(int s=0;s<16;s++){ A[s] = -__expf(alog[d*16+s]); h[s] = b2f(hbuf[s]); }
  float Dd = Dp[d];
  float dtv[16], xiv[16], zsv[16];
  #pragma unroll
  for(int i=0;i<CHL;i++){
    dtv[i] = b2f(dt[(size_t)(pbase+i)*128 + d]);
    xiv[i] = b2f(xi[(size_t)(pbase+i)*128 + d]);
    zsv[i] = b2f(zs[(size_t)(pbase+i)*128 + d]);
  }
  __syncthreads();
  #pragma unroll
  for(int i=0;i<CHL;i++){
    float Bv[16], Cv[16];
    unpack16(*(const uint4*)(sbc + i*32),      *(const uint4*)(sbc + i*32 + 8),  Bv);
    unpack16(*(const uint4*)(sbc + i*32 + 16), *(const uint4*)(sbc + i*32 + 24), Cv);
    float u = dtv[i]*xiv[i];
    float acc = Dd*xiv[i];
    #pragma unroll
    for(int s=0;s<16;s++){
      float a = __expf(dtv[i]*A[s]);
      h[s] = a*h[s] + u*Bv[s];
      acc += h[s]*Cv[s];
    }
    sY[i*LDY + d] = f2b(acc * zsv[i]);
  }
  __syncthreads();
  int ln = tid & 63, wv = tid >> 6;
  int mrow = ln & 15, quad = ln >> 4;
  f4v acc2[2];
  acc2[0] = (f4v){0.f,0.f,0.f,0.f};
  acc2[1] = (f4v){0.f,0.f,0.f,0.f};
  #pragma unroll
  for(int kk=0; kk<128; kk+=32){
    s8v af = *(const s8v*)(sY + mrow*LDY + kk + quad*8);
    #pragma unroll
    for(int ns=0; ns<2; ns++){
      int n0 = wv*32 + ns*16;
      s8v bf = *(const s8v*)(sWo + (n0+mrow)*LDW + kk + quad*8);
      acc2[ns] = __builtin_amdgcn_mfma_f32_16x16x32_bf16(af, bf, acc2[ns], 0, 0, 0);
    }
  }
  #pragma unroll
  for(int ns=0; ns<2; ns++){
    int n = wv*32 + ns*16 + mrow;
    #pragma unroll
    for(int r=0;r<4;r++){
      int px = pbase + quad*4 + r;
      y[(size_t)px*64 + n] = f2b(acc2[ns][r] + b2f(x0[(size_t)px*64 + n]));
    }
  }
}

// ========== MFMA with fused LayerNorm on A (CIN=64) ==========
template<int COUT, int ACT>
__global__ __launch_bounds__(256) void k_mfma_ln(const u16* __restrict__ wT,
                     const u16* __restrict__ in, const float* __restrict__ g,
                     const float* __restrict__ bta, u16* __restrict__ outp){
  const int CIN = 64, LDA = 72, NS = COUT/16;
  __shared__ __align__(16) u16 sA[64*LDA];
  __shared__ __align__(16) u16 sW[COUT*LDA];
  int tid = threadIdx.x;
  int p0 = blockIdx.x * 64;
  int ln = tid & 63, wv = tid >> 6;
  int mrow = ln & 15, quad = ln >> 4;
  for(int idx=tid; idx<COUT*8; idx+=256){
    int n = idx>>3, c8 = (idx&7)*8;
    *(uint4*)(sW + n*LDA + c8) = *(const uint4*)(wT + n*64 + c8);
  }
  float gg = g[ln], bb = bta[ln];
  #pragma unroll
  for(int i=0;i<16;i++){
    int row = wv*16 + i;
    float v = b2f(in[(size_t)(p0+row)*64 + ln]);
    float s = v, sq = v*v;
    #pragma unroll
    for(int o=32;o>0;o>>=1){ s += __shfl_xor(s,o); sq += __shfl_xor(sq,o); }
    float m = s*(1.f/64.f);
    float var = sq*(1.f/64.f) - m*m;
    float r = rsqrtf(var + 1e-5f);
    sA[row*LDA + ln] = f2b((v-m)*r*gg + bb);
  }
  __syncthreads();
  f4v acc[NS];
  #pragma unroll
  for(int i=0;i<NS;i++) acc[i] = (f4v){0.f,0.f,0.f,0.f};
  const u16* aBase = sA + (wv*16 + mrow)*LDA + quad*8;
  const u16* wBase = sW + mrow*LDA + quad*8;
  #pragma unroll
  for(int kk=0; kk<CIN; kk+=32){
    s8v af = *(const s8v*)(aBase + kk);
    #pragma unroll
    for(int ns=0; ns<NS; ns++){
      s8v bf = *(const s8v*)(wBase + ns*16*LDA + kk);
      acc[ns] = __builtin_amdgcn_mfma_f32_16x16x32_bf16(af, bf, acc[ns], 0, 0, 0);
    }
  }
  int pr = p0 + wv*16 + quad*4;
  #pragma unroll
  for(int ns=0; ns<NS; ns++){
    int n = ns*16 + mrow;
    #pragma unroll
    for(int r=0;r<4;r++){
      float v = acc[ns][r];
      if(ACT==1) v = leaky02(v);
      outp[(size_t)(pr+r)*COUT + n] = f2b(v);
    }
  }
}

// ========== final MFMA: [NPIX,256] @ wf2t[64][256] + res, fp32 NCHW store ==========
__global__ __launch_bounds__(256) void k_mfma_fin(const u16* __restrict__ wT,
                     const u16* __restrict__ in, const u16* __restrict__ res,
                     float* __restrict__ outp){
  const int CIN=256, COUT=64, KCH=128, LDA=136, NS=4;
  __shared__ __align__(16) u16 sA[64*LDA];
  __shared__ __align__(16) u16 sW[COUT*LDA];
  int tid = threadIdx.x;
  int p0 = blockIdx.x * 64;
  int ln = tid & 63, wv = tid >> 6;
  int mrow = ln & 15, quad = ln >> 4;
  f4v acc[NS];
  #pragma unroll
  for(int i=0;i<NS;i++) acc[i] = (f4v){0.f,0.f,0.f,0.f};
  const u16* aBase = sA + (wv*16 + mrow)*LDA + quad*8;
  const u16* wBase = sW + mrow*LDA + quad*8;
  for(int k0=0; k0<CIN; k0+=KCH){
    if(k0) __syncthreads();
    for(int idx=tid; idx<COUT*16; idx+=256){
      int n = idx>>4, c8 = (idx&15)*8;
      *(uint4*)(sW + n*LDA + c8) = *(const uint4*)(wT + n*256 + k0 + c8);
    }
    for(int g=tid; g<64*16; g+=256){
      int row = g >> 4, c8 = (g & 15)*8;
      *(uint4*)(sA + row*LDA + c8) = *(const uint4*)(in + (size_t)(p0+row)*CIN + k0 + c8);
    }
    __syncthreads();
    #pragma unroll
    for(int kk=0; kk<KCH; kk+=32){
      s8v af = *(const s8v*)(aBase + kk);
      #pragma unroll
      for(int ns=0; ns<NS; ns++){
        s8v bf = *(const s8v*)(wBase + ns*16*LDA + kk);
        acc[ns] = __builtin_amdgcn_mfma_f32_16x16x32_bf16(af, bf, acc[ns], 0, 0, 0);
      }
    }
  }
  int pr = p0 + wv*16 + quad*4;
  int b = blockIdx.x >> 6;
  int hwr = ((blockIdx.x & 63) << 6) + wv*16 + quad*4;
  #pragma unroll
  for(int ns=0; ns<NS; ns++){
    int n = ns*16 + mrow;
    float4 v4;
    v4.x = acc[ns][0] + b2f(res[(size_t)(pr+0)*64 + n]);
    v4.y = acc[ns][1] + b2f(res[(size_t)(pr+1)*64 + n]);
    v4.z = acc[ns][2] + b2f(res[(size_t)(pr+2)*64 + n]);
    v4.w = acc[ns][3] + b2f(res[(size_t)(pr+3)*64 + n]);
    *(float4*)(outp + (size_t)b*C_*HW_ + (size_t)n*HW_ + hwr) = v4;
  }
}

// ---------------- depthwise 3x3 SAME, 4 channels per thread ----------------
template<int CN, int ACT>
__global__ void k_dw3(const u16* __restrict__ in, const float* __restrict__ wgt,
                      const u16* __restrict__ res1, const u16* __restrict__ res2,
                      u16* __restrict__ out){
  const int C4 = CN/4;
  int g = blockIdx.x*256 + threadIdx.x;
  int c4 = g % C4;
  int pix = g / C4;
  int w = pix & 63;
  int h = (pix >> 6) & 63;
  int b = pix >> 12;
  float a0=0.f, a1=0.f, a2=0.f, a3=0.f;
  #pragma unroll
  for(int kh=0;kh<3;kh++){
    int hh = h + kh - 1;
    if((unsigned)hh < 64u){
      #pragma unroll
      for(int kw=0;kw<3;kw++){
        int ww = w + kw - 1;
        if((unsigned)ww < 64u){
          ushort4 v = *(const ushort4*)(in + (size_t)((b*64+hh)*64 + ww)*CN + c4*4);
          float4 wv = *(const float4*)(wgt + (kh*3+kw)*CN + c4*4);
          a0 += b2f(v.x)*wv.x; a1 += b2f(v.y)*wv.y;
          a2 += b2f(v.z)*wv.z; a3 += b2f(v.w)*wv.w;
        }
      }
    }
  }
  if(ACT==1){ a0=leaky02(a0); a1=leaky02(a1); a2=leaky02(a2); a3=leaky02(a3); }
  else if(ACT==2){ a0=gelu_exact(a0); a1=gelu_exact(a1); a2=gelu_exact(a2); a3=gelu_exact(a3); }
  size_t ob = (size_t)pix*CN + c4*4;
  if(res1){ ushort4 r = *(const ushort4*)(res1 + ob);
            a0+=b2f(r.x); a1+=b2f(r.y); a2+=b2f(r.z); a3+=b2f(r.w); }
  if(res2){ ushort4 r = *(const ushort4*)(res2 + ob);
            a0+=b2f(r.x); a1+=b2f(r.y); a2+=b2f(r.z); a3+=b2f(r.w); }
  ushort4 o; o.x=f2b(a0); o.y=f2b(a1); o.z=f2b(a2); o.w=f2b(a3);
  *(ushort4*)(out + ob) = o;
}

extern "C" void kernel_launch(void* const* d_in, const int* in_sizes, int n_in,
                              void* d_out, int out_size, void* d_ws, size_t ws_size,
                              hipStream_t stream) {
  const float* x        = (const float*)d_in[0];
  const float* ln1_g    = (const float*)d_in[1];
  const float* ln1_b    = (const float*)d_in[2];
  const float* vin_w1   = (const float*)d_in[3];
  const float* vin_dw   = (const float*)d_in[4];
  const float* vin_w2   = (const float*)d_in[5];
  const float* vout_dw1 = (const float*)d_in[6];
  const float* vout_dw2 = (const float*)d_in[7];
  const float* ssm_in_w = (const float*)d_in[8];
  const float* ssm_cw   = (const float*)d_in[9];
  const float* ssm_cb   = (const float*)d_in[10];
  const float* ssm_xprj = (const float*)d_in[11];
  const float* ssm_dtw  = (const float*)d_in[12];
  const float* ssm_dtb  = (const float*)d_in[13];
  const float* ssm_Alog = (const float*)d_in[14];
  const float* ssm_D    = (const float*)d_in[15];
  const float* ssm_outw = (const float*)d_in[16];
  const float* ln2_g    = (const float*)d_in[17];
  const float* ln2_b    = (const float*)d_in[18];
  const float* ff_w1    = (const float*)d_in[19];
  const float* ff_dw    = (const float*)d_in[20];
  const float* ff_w2    = (const float*)d_in[21];
  float* out = (float*)d_out;

  // ---- bf16 arena, lifetime-packed (units: bf16 elements) ----
  const size_t M = 1u<<20;
  u16* U   = (u16*)d_ws;
  u16* xT  = U;              // [0,2M)
  u16* tA  = U + 2*M;        // [2M,4M)   Hin during scan
  u16* tB  = U + 4*M;        // [4M,6M)
  u16* x0  = U + 6*M;        // [6M,8M)   x0, later xR
  u16* xi  = U + 8*M;        // [8M,12M)
  u16* zs  = U + 12*M;       // [12M,16M)
  u16* xz  = U + 16*M;       // [16M,24M) Pb/Qb; y; t1
  u16* dtb = U + 24*M;       // [24M,28M) dt; t2
  u16* bc  = U + 28*M;       // [28M,29M)
  u16* Pb  = U + 16*M;       // [16M,20M)
  u16* Qb  = U + 20*M;       // [20M,24M)
  u16* Hin = tA;             // [2M,6M)
  u16* y   = U + 16*M;       // [16M,18M)
  u16* t2  = dtb;            // [24M,32M)
  // pre-transposed bf16 weights:
  u16* wv1  = U + 33*M;
  u16* wv2  = wv1 + 4096;
  u16* wsi  = wv2 + 4096;
  u16* wdb  = wsi + 16384;
  u16* wout = wdb + 20480;
  u16* wf1  = wout + 8192;
  u16* wf2t = wf1 + 16384;

  k_prep<<<80,256,0,stream>>>(vin_w1, vin_w2, ssm_in_w, ssm_xprj, ssm_dtw, ssm_outw,
                              ff_w1, ff_w2, wv1, wv2, wsi, wdb, wout, wf1, wf2t);

  // --- vision in path ---
  k_trans_ln_mm<<<512,256,0,stream>>>(x, ln1_g, ln1_b, wv1, xT, tB);
  k_dw3<64,2><<<2048,256,0,stream>>>(tB, vin_dw, nullptr, nullptr, tA);
  k_mfma<64,64,0,false><<<512,256,0,stream>>>(wv2, tA, nullptr, nullptr, x0);

  // --- SSM (ssm_in + conv + dt/bc fused) ---
  k_ssm_dtbc<<<512,256,0,stream>>>(wsi, x0, ssm_cw, ssm_cb, wdb, ssm_dtb,
                                   xi, zs, dtb, bc);
  k_scan1<<<1024,256,0,stream>>>(dtb, xi, bc, ssm_Alog, Pb, Qb);
  k_scan2<<<128,64,0,stream>>>(Pb, Qb, Hin);
  k_scan3_mm<<<2048,128,0,stream>>>(dtb, xi, bc, zs, ssm_Alog, ssm_D, Hin, wout, x0, y);

  // --- vision out path:  xR = dw2(gelu(dw1(y))) + y + xT ---
  k_dw3<64,2><<<2048,256,0,stream>>>(y, vout_dw1, nullptr, nullptr, tA);
  k_dw3<64,0><<<2048,256,0,stream>>>(tA, vout_dw2, y, xT, x0);   // x0 now = xR

  // --- FFN ---
  k_mfma_ln<256,1><<<512,256,0,stream>>>(wf1, x0, ln2_g, ln2_b, xz);  // t1
  k_dw3<256,1><<<8192,256,0,stream>>>(xz, ff_dw, nullptr, nullptr, t2);
  k_mfma_fin<<<512,256,0,stream>>>(wf2t, t2, x0, out);
}

// Round 17
// 274.719 us; speedup vs baseline: 1.0484x; 1.0246x over previous
//
#include <hip/hip_runtime.h>
#include <hip/hip_bf16.h>
#include <math.h>

typedef unsigned short u16;   // bf16 storage
typedef __attribute__((ext_vector_type(8))) short s8v;    // 8 bf16 = 4 VGPR
typedef __attribute__((ext_vector_type(4))) float f4v;    // MFMA acc

#define B_    8
#define C_    64
#define HW_   4096
#define NPIX  32768     // B_*HW_
#define DI    128
#define NCH   256
#define CHL   16        // HW_/NCH

__device__ __forceinline__ float b2f(u16 v){ return __uint_as_float(((unsigned)v)<<16); }
__device__ __forceinline__ u16 f2b(float x){
  unsigned u = __float_as_uint(x);
  u += 0x7fff + ((u >> 16) & 1);      // RTNE
  return (u16)(u >> 16);
}
__device__ __forceinline__ float gelu_exact(float x){ return 0.5f*x*(1.0f+erff(x*0.70710678118654752f)); }
__device__ __forceinline__ float leaky02(float x){ return x>0.f ? x : 0.2f*x; }
__device__ __forceinline__ float softplus_(float x){ return fmaxf(x,0.f)+log1pf(__expf(-fabsf(x))); }
__device__ __forceinline__ float silu_(float x){ return x / (1.0f + __expf(-x)); }
__device__ __forceinline__ void unpack16(uint4 q0, uint4 q1, float* v){
  unsigned w[8]={q0.x,q0.y,q0.z,q0.w,q1.x,q1.y,q1.z,q1.w};
  #pragma unroll
  for(int j=0;j<8;j++){
    v[2*j]   = __uint_as_float(w[j]<<16);
    v[2*j+1] = __uint_as_float(w[j]&0xffff0000u);
  }
}

// ====== prep: all weights -> bf16 transposed [COUT][CIN]; W2 fused (xproj/dtw) ======
__global__ void k_prep(const float* __restrict__ vin_w1, const float* __restrict__ vin_w2,
                       const float* __restrict__ ssm_in_w, const float* __restrict__ xproj,
                       const float* __restrict__ dtw, const float* __restrict__ ssm_outw,
                       const float* __restrict__ ff_w1, const float* __restrict__ ff_w2,
                       u16* __restrict__ wv1, u16* __restrict__ wv2, u16* __restrict__ wsi,
                       u16* __restrict__ wdb, u16* __restrict__ wout, u16* __restrict__ wf1,
                       u16* __restrict__ wf2t){
  int g = blockIdx.x*256 + threadIdx.x;     // 80*256 = 20480
  if(g < 4096){
    int n=g>>6, c=g&63;
    wv1[n*64+c]=f2b(vin_w1[c*64+n]);
    wv2[n*64+c]=f2b(vin_w2[c*64+n]);
  }
  if(g < 16384){
    int n=g>>6, c=g&63;
    wsi[n*64+c]=f2b(ssm_in_w[c*256+n]);
    wf1[n*64+c]=f2b(ff_w1[c*256+n]);
    int n2=g/256, k2=g%256;
    wf2t[n2*256+k2]=f2b(ff_w2[k2*64+n2]);
  }
  if(g < 8192){
    int n=g>>7, k=g&127;
    wout[n*128+k]=f2b(ssm_outw[k*64+n]);
  }
  if(g < 20480){
    int n=g/128, k=g%128;
    float v;
    if(n < 128){
      v = 0.f;
      for(int r=0;r<4;r++) v += xproj[k*36+r]*dtw[r*128+n];
    }else{
      v = xproj[k*36+4+(n-128)];
    }
    wdb[n*128+k]=f2b(v);
  }
}

// ====== fused: NCHW fp32 -> (xT bf16 NHWC) + LayerNorm + vin_w1 MFMA -> outp ======
__global__ __launch_bounds__(256) void k_trans_ln_mm(const float* __restrict__ x,
                     const float* __restrict__ g, const float* __restrict__ bta,
                     const u16* __restrict__ wT,
                     u16* __restrict__ xT, u16* __restrict__ outp){
  const int LDA = 72, NS = 4;
  __shared__ float tile[64][65];
  __shared__ __align__(16) u16 sA[64*LDA];
  __shared__ __align__(16) u16 sW[64*LDA];
  int tid = threadIdx.x;
  int blk = blockIdx.x;            // 512
  int b = blk >> 6;
  int hwb = (blk & 63) << 6;
  int lane = tid & 63, row = tid >> 6;
  const float* src = x + (size_t)b*C_*HW_;
  #pragma unroll
  for(int k=0;k<16;k++){
    int c = row + 4*k;
    tile[c][lane] = src[c*HW_ + hwb + lane];
  }
  for(int idx=tid; idx<64*8; idx+=256){
    int n = idx>>3, c8 = (idx&7)*8;
    *(uint4*)(sW + n*LDA + c8) = *(const uint4*)(wT + n*64 + c8);
  }
  __syncthreads();
  u16* dstT = xT + (size_t)b*HW_*C_;
  #pragma unroll
  for(int k=0;k<16;k++){
    int hwl = row + 4*k;
    dstT[(hwb+hwl)*C_ + lane] = f2b(tile[lane][hwl]);
  }
  float gg = g[lane], bb = bta[lane];
  #pragma unroll
  for(int i=0;i<16;i++){
    int hwl = row*16 + i;
    float v = tile[lane][hwl];
    float s = v, sq = v*v;
    #pragma unroll
    for(int o=32;o>0;o>>=1){ s += __shfl_xor(s,o); sq += __shfl_xor(sq,o); }
    float m = s*(1.f/64.f);
    float var = sq*(1.f/64.f) - m*m;
    float r = rsqrtf(var + 1e-5f);
    sA[hwl*LDA + lane] = f2b((v-m)*r*gg + bb);
  }
  __syncthreads();
  int ln = tid & 63, wv = tid >> 6;
  int mrow = ln & 15, quad = ln >> 4;
  f4v acc[NS];
  #pragma unroll
  for(int i=0;i<NS;i++) acc[i] = (f4v){0.f,0.f,0.f,0.f};
  const u16* aBase = sA + (wv*16 + mrow)*LDA + quad*8;
  const u16* wBase = sW + mrow*LDA + quad*8;
  #pragma unroll
  for(int kk=0; kk<64; kk+=32){
    s8v af = *(const s8v*)(aBase + kk);
    #pragma unroll
    for(int ns=0; ns<NS; ns++){
      s8v bf = *(const s8v*)(wBase + ns*16*LDA + kk);
      acc[ns] = __builtin_amdgcn_mfma_f32_16x16x32_bf16(af, bf, acc[ns], 0, 0, 0);
    }
  }
  int p0 = blk*64;
  int pr = p0 + wv*16 + quad*4;
  #pragma unroll
  for(int ns=0; ns<NS; ns++){
    int n = ns*16 + mrow;
    #pragma unroll
    for(int r=0;r<4;r++)
      outp[(size_t)(pr+r)*64 + n] = f2b(acc[ns][r]);
  }
}

// ====== fused vin: dw3+gelu + 1x1 (wv2) MFMA; 512 blocks, 8x8 tile ======
__global__ __launch_bounds__(256) void k_dw3mm(const u16* __restrict__ in,
                     const float* __restrict__ dwgt, const u16* __restrict__ wT,
                     u16* __restrict__ x0){
  const int LDT = 72;
  __shared__ __align__(16) u16 sIn[10*10*64];    // 12.8 KB
  __shared__ __align__(16) u16 sT[64*LDT];       // 9.2 KB
  __shared__ __align__(16) u16 sW[64*LDT];       // 9.2 KB
  int tid = threadIdx.x;
  int blk = blockIdx.x;            // 512
  int b = blk >> 6;
  int t6 = blk & 63;
  int h0 = (t6 >> 3) * 8, w0 = (t6 & 7) * 8;
  for(int idx=tid; idx<64*8; idx+=256){
    int n = idx>>3, c8 = (idx&7)*8;
    *(uint4*)(sW + n*LDT + c8) = *(const uint4*)(wT + n*64 + c8);
  }
  for(int q=tid; q<10*10*16; q+=256){
    int pp = q >> 4, c4 = q & 15;
    int hh = pp / 10, ww = pp % 10;
    int gh = h0-1+hh, gw = w0-1+ww;
    ushort4 v = make_ushort4(0,0,0,0);
    if((unsigned)gh < 64u && (unsigned)gw < 64u)
      v = *(const ushort4*)(in + (size_t)((b*64+gh)*64+gw)*64 + c4*4);
    *(ushort4*)(sIn + pp*64 + c4*4) = v;
  }
  __syncthreads();
  int c4 = tid & 15;
  #pragma unroll
  for(int pass=0; pass<4; pass++){
    int opix = pass*16 + (tid>>4);
    int oh = opix >> 3, ow = opix & 7;
    float a0=0.f,a1=0.f,a2=0.f,a3=0.f;
    #pragma unroll
    for(int kh=0;kh<3;kh++){
      #pragma unroll
      for(int kw=0;kw<3;kw++){
        ushort4 v = *(const ushort4*)(sIn + ((oh+kh)*10 + (ow+kw))*64 + c4*4);
        float4 wv = *(const float4*)(dwgt + (kh*3+kw)*64 + c4*4);
        a0 += b2f(v.x)*wv.x; a1 += b2f(v.y)*wv.y;
        a2 += b2f(v.z)*wv.z; a3 += b2f(v.w)*wv.w;
      }
    }
    ushort4 o; o.x=f2b(gelu_exact(a0)); o.y=f2b(gelu_exact(a1));
    o.z=f2b(gelu_exact(a2)); o.w=f2b(gelu_exact(a3));
    *(ushort4*)(sT + opix*LDT + c4*4) = o;
  }
  __syncthreads();
  int ln = tid & 63, wv = tid >> 6;
  int mrow = ln & 15, quad = ln >> 4;
  f4v acc[4];
  #pragma unroll
  for(int i=0;i<4;i++) acc[i] = (f4v){0.f,0.f,0.f,0.f};
  const u16* aBase = sT + (wv*16 + mrow)*LDT + quad*8;
  const u16* wBase = sW + mrow*LDT + quad*8;
  #pragma unroll
  for(int kk=0; kk<64; kk+=32){
    s8v af = *(const s8v*)(aBase + kk);
    #pragma unroll
    for(int ns=0; ns<4; ns++){
      s8v bf = *(const s8v*)(wBase + ns*16*LDT + kk);
      acc[ns] = __builtin_amdgcn_mfma_f32_16x16x32_bf16(af, bf, acc[ns], 0, 0, 0);
    }
  }
  #pragma unroll
  for(int ns=0; ns<4; ns++){
    int n = ns*16 + mrow;
    #pragma unroll
    for(int r=0;r<4;r++){
      int opix = wv*16 + quad*4 + r;
      int oh = opix >> 3, ow = opix & 7;
      size_t p = ((size_t)(b*64 + h0+oh)*64 + (w0+ow));
      x0[p*64 + n] = f2b(acc[ns][r]);
    }
  }
}

// ========== generic MFMA matmul: [NPIX,CIN](bf16) @ wT[COUT][CIN](bf16) ==========
template<int CIN, int COUT, int ACT, bool OUTF32>
__global__ __launch_bounds__(256) void k_mfma(const u16* __restrict__ wT,
                     const u16* __restrict__ in, const float* __restrict__ bias,
                     const u16* __restrict__ res, void* __restrict__ outv){
  const int KCH = (CIN < 128) ? CIN : 128;
  const int LDA = KCH + 8;
  const int NS  = COUT / 16;
  __shared__ __align__(16) u16 sA[64*LDA];
  __shared__ __align__(16) u16 sW[COUT*LDA];
  int tid = threadIdx.x;
  int p0 = blockIdx.x * 64;
  int ln = tid & 63, wv = tid >> 6;
  int mrow = ln & 15, quad = ln >> 4;
  f4v acc[NS];
  #pragma unroll
  for(int i=0;i<NS;i++) acc[i] = (f4v){0.f,0.f,0.f,0.f};
  const u16* aBase = sA + (wv*16 + mrow)*LDA + quad*8;
  const u16* wBase = sW + mrow*LDA + quad*8;
  const int RW = KCH/8;
  for(int k0=0; k0<CIN; k0+=KCH){
    if(k0) __syncthreads();
    for(int idx=tid; idx<COUT*RW; idx+=256){
      int n = idx/RW, c8 = (idx%RW)*8;
      *(uint4*)(sW + n*LDA + c8) = *(const uint4*)(wT + (size_t)n*CIN + k0 + c8);
    }
    for(int g=tid; g<64*RW; g+=256){
      int row = g / RW, c8 = (g % RW)*8;
      *(uint4*)(sA + row*LDA + c8) = *(const uint4*)(in + (size_t)(p0+row)*CIN + k0 + c8);
    }
    __syncthreads();
    #pragma unroll
    for(int kk=0; kk<KCH; kk+=32){
      s8v af = *(const s8v*)(aBase + kk);
      #pragma unroll
      for(int ns=0; ns<NS; ns++){
        s8v bf = *(const s8v*)(wBase + ns*16*LDA + kk);
        acc[ns] = __builtin_amdgcn_mfma_f32_16x16x32_bf16(af, bf, acc[ns], 0, 0, 0);
      }
    }
  }
  int pr = p0 + wv*16 + quad*4;
  #pragma unroll
  for(int ns=0; ns<NS; ns++){
    int n = ns*16 + mrow;
    float bs = bias ? bias[n] : 0.f;
    #pragma unroll
    for(int r=0;r<4;r++){
      float v = acc[ns][r] + bs;
      if(ACT==1) v = leaky02(v);
      else if(ACT==2) v = softplus_(v);
      if(res) v += b2f(res[(size_t)(pr+r)*COUT + n]);
      if(OUTF32) ((float*)outv)[(size_t)(pr+r)*COUT + n] = v;
      else       ((u16*)outv)[(size_t)(pr+r)*COUT + n] = f2b(v);
    }
  }
}

// ====== fused: ssm_in matmul + causal conv + silu + dt/bc MFMA (xi tile stays in LDS) ======
__global__ __launch_bounds__(256) void k_ssm_dtbc(const u16* __restrict__ wT,
                     const u16* __restrict__ x0,
                     const float* __restrict__ cw, const float* __restrict__ cb,
                     const u16* __restrict__ wdb, const float* __restrict__ dtbias,
                     u16* __restrict__ xi, u16* __restrict__ zs,
                     u16* __restrict__ dtout, u16* __restrict__ bcout){
  const int LDA=72, NS=16, LDY=136, LDWD=136, NS2=10;
  __shared__ __align__(16) u16 S[31616];
  u16* sW   = S;
  u16* sA   = S + 18432;
  u16* ubuf = S + 23040;
  u16* xiT  = S;
  u16* wdbS = S + 8704;
  int tid = threadIdx.x;
  int p0 = blockIdx.x*64;
  int ln = tid & 63, wv = tid >> 6;
  int mrow = ln & 15, quad = ln >> 4;
  for(int idx=tid; idx<256*8; idx+=256){
    int n = idx>>3, c8 = (idx&7)*8;
    *(uint4*)(sW + n*LDA + c8) = *(const uint4*)(wT + n*64 + c8);
  }
  for(int g=tid; g<64*8; g+=256){
    int row = g >> 3, c8 = (g & 7)*8;
    *(uint4*)(sA + row*LDA + c8) = *(const uint4*)(x0 + (size_t)(p0+row)*64 + c8);
  }
  __syncthreads();
  f4v acc[NS];
  #pragma unroll
  for(int i=0;i<NS;i++) acc[i] = (f4v){0.f,0.f,0.f,0.f};
  const u16* aBase = sA + (wv*16 + mrow)*LDA + quad*8;
  const u16* wBase = sW + mrow*LDA + quad*8;
  #pragma unroll
  for(int kk=0; kk<64; kk+=32){
    s8v af = *(const s8v*)(aBase + kk);
    #pragma unroll
    for(int ns=0; ns<NS; ns++){
      s8v bf = *(const s8v*)(wBase + ns*16*LDA + kk);
      acc[ns] = __builtin_amdgcn_mfma_f32_16x16x32_bf16(af, bf, acc[ns], 0, 0, 0);
    }
  }
  bool bstart = ((p0 & 4095) == 0);
  for(int idx=tid; idx<384; idx+=256){
    int j = idx >> 7, n = idx & 127;
    float a2 = 0.f;
    if(!bstart){
      const u16* xr = x0 + (size_t)(p0-3+j)*64;
      #pragma unroll 8
      for(int c=0;c<64;c++) a2 += b2f(xr[c]) * b2f(sW[n*LDA+c]);
    }
    ubuf[j*128 + n] = f2b(a2);
  }
  int prl = wv*16 + quad*4;
  #pragma unroll
  for(int ns=0; ns<NS; ns++){
    int n = ns*16 + mrow;
    if(n < 128){
      #pragma unroll
      for(int r=0;r<4;r++) ubuf[(prl+r+3)*128 + n] = f2b(acc[ns][r]);
    }else{
      #pragma unroll
      for(int r=0;r<4;r++) zs[(size_t)(p0+prl+r)*128 + (n-128)] = f2b(silu_(acc[ns][r]));
    }
  }
  __syncthreads();   // ubuf complete; sW/sA now dead
  int d4 = tid & 31;
  float4 cbv = *(const float4*)(cb + d4*4);
  for(int row = tid >> 5; row < 64; row += 8){
    float a0=cbv.x, a1=cbv.y, a2=cbv.z, a3=cbv.w;
    #pragma unroll
    for(int k=0;k<4;k++){
      ushort4 v = *(const ushort4*)(ubuf + (row+k)*128 + d4*4);
      float4 wv4 = *(const float4*)(cw + k*128 + d4*4);
      a0 += b2f(v.x)*wv4.x; a1 += b2f(v.y)*wv4.y;
      a2 += b2f(v.z)*wv4.z; a3 += b2f(v.w)*wv4.w;
    }
    ushort4 o; o.x=f2b(silu_(a0)); o.y=f2b(silu_(a1)); o.z=f2b(silu_(a2)); o.w=f2b(silu_(a3));
    *(ushort4*)(xi + (size_t)(p0+row)*128 + d4*4) = o;
    *(ushort4*)(xiT + row*LDY + d4*4) = o;
  }
  __syncthreads();   // ubuf dead; xiT complete
  for(int idx=tid; idx<160*16; idx+=256){
    int n = idx>>4, c8 = (idx&15)*8;
    *(uint4*)(wdbS + n*LDWD + c8) = *(const uint4*)(wdb + n*128 + c8);
  }
  __syncthreads();
  f4v acc2[NS2];
  #pragma unroll
  for(int i=0;i<NS2;i++) acc2[i] = (f4v){0.f,0.f,0.f,0.f};
  #pragma unroll
  for(int kk=0; kk<128; kk+=32){
    s8v af = *(const s8v*)(xiT + (wv*16+mrow)*LDY + kk + quad*8);
    #pragma unroll
    for(int ns=0; ns<NS2; ns++){
      s8v bf = *(const s8v*)(wdbS + (ns*16+mrow)*LDWD + kk + quad*8);
      acc2[ns] = __builtin_amdgcn_mfma_f32_16x16x32_bf16(af, bf, acc2[ns], 0, 0, 0);
    }
  }
  int pr = p0 + wv*16 + quad*4;
  #pragma unroll
  for(int ns=0; ns<NS2; ns++){
    int n = ns*16 + mrow;
    if(n < 128){
      float bs = dtbias[n];
      #pragma unroll
      for(int r=0;r<4;r++)
        dtout[(size_t)(pr+r)*128 + n] = f2b(softplus_(acc2[ns][r] + bs));
    }else{
      #pragma unroll
      for(int r=0;r<4;r++)
        bcout[(size_t)(pr+r)*32 + (n-128)] = f2b(acc2[ns][r]);
    }
  }
}

// ====== scan phase 1: LDS-free, 1 chunk/thread ======
__global__ __launch_bounds__(256) void k_scan1(const u16* __restrict__ dt, const u16* __restrict__ xi,
                        const u16* __restrict__ bc, const float* __restrict__ alog,
                        u16* __restrict__ Pb, u16* __restrict__ Qb){
  int t = blockIdx.x*256 + threadIdx.x;    // 1024 blocks
  int d = t & 127;
  int ch = (t >> 7) & 255;
  int b = t >> 15;
  int pbase = b*HW_ + ch*CHL;
  float A[16];
  #pragma unroll
  for(int s=0;s<16;s++) A[s] = -__expf(alog[d*16+s]);
  float dtv[16], uv[16];
  #pragma unroll
  for(int i=0;i<CHL;i++){
    dtv[i] = b2f(dt[(size_t)(pbase+i)*128 + d]);
    uv[i]  = dtv[i] * b2f(xi[(size_t)(pbase+i)*128 + d]);
  }
  float Q[16], sumdt = 0.f;
  #pragma unroll
  for(int s=0;s<16;s++) Q[s] = 0.f;
  #pragma unroll
  for(int i=0;i<CHL;i++){
    float Bv[16];
    unpack16(*(const uint4*)(bc + (size_t)(pbase+i)*32),
             *(const uint4*)(bc + (size_t)(pbase+i)*32 + 8), Bv);
    sumdt += dtv[i];
    #pragma unroll
    for(int s=0;s<16;s++){
      float a = __expf(dtv[i]*A[s]);
      Q[s] = a*Q[s] + uv[i]*Bv[s];
    }
  }
  int gidx = ch*16384 + (b*128+d)*16;
  unsigned pw[8], qw[8];
  #pragma unroll
  for(int j=0;j<8;j++){
    pw[j] = (unsigned)f2b(__expf(A[2*j]*sumdt)) | ((unsigned)f2b(__expf(A[2*j+1]*sumdt))<<16);
    qw[j] = (unsigned)f2b(Q[2*j]) | ((unsigned)f2b(Q[2*j+1])<<16);
  }
  *(uint4*)(Pb+gidx)   = make_uint4(pw[0],pw[1],pw[2],pw[3]);
  *(uint4*)(Pb+gidx+8) = make_uint4(pw[4],pw[5],pw[6],pw[7]);
  *(uint4*)(Qb+gidx)   = make_uint4(qw[0],qw[1],qw[2],qw[3]);
  *(uint4*)(Qb+gidx+8) = make_uint4(qw[4],qw[5],qw[6],qw[7]);
}

// ---------------- scan phase 2 (2 sequences per thread) ----------------
__global__ void k_scan2(const u16* __restrict__ Pb, const u16* __restrict__ Qb,
                        u16* __restrict__ Hin){
  int g2 = (blockIdx.x*64 + threadIdx.x)*2;
  float h0 = 0.f, h1 = 0.f;
  #pragma unroll 8
  for(int ch=0; ch<NCH; ch++){
    unsigned p = *(const unsigned*)(Pb + ch*16384 + g2);
    unsigned q = *(const unsigned*)(Qb + ch*16384 + g2);
    *(unsigned*)(Hin + ch*16384 + g2) = (unsigned)f2b(h0) | ((unsigned)f2b(h1)<<16);
    h0 = __uint_as_float(p<<16)*h0 + __uint_as_float(q<<16);
    h1 = __uint_as_float(p&0xffff0000u)*h1 + __uint_as_float(q&0xffff0000u);
  }
}

// ------- scan phase 3 (global column loads) + out-proj MFMA -------
__global__ __launch_bounds__(128) void k_scan3_mm(const u16* __restrict__ dt, const u16* __restrict__ xi,
                        const u16* __restrict__ bc, const u16* __restrict__ zs,
                        const float* __restrict__ alog, const float* __restrict__ Dp,
                        const u16* __restrict__ Hin, const u16* __restrict__ wout,
                        const u16* __restrict__ x0, u16* __restrict__ y){
  const int LDY = 136, LDW = 136;
  int blk = blockIdx.x;
  int ch = blk & (NCH-1);
  int b = blk >> 8;
  int d = threadIdx.x, tid = threadIdx.x;
  __shared__ __align__(16) u16 sY[CHL*LDY];
  __shared__ __align__(16) u16 sWo[64*LDW];
  __shared__ __align__(16) u16 sbc[CHL*32];
  for(int idx=tid; idx<64*16; idx+=128){
    int n = idx>>4, c8 = (idx&15)*8;
    *(uint4*)(sWo + n*LDW + c8) = *(const uint4*)(wout + n*128 + c8);
  }
  int pbase = b*HW_ + ch*CHL;
  if(tid < 64) ((uint4*)sbc)[tid] = ((const uint4*)(bc + (size_t)pbase*32))[tid];
  float A[16], h[16];
  u16 hbuf[16];
  int gidx = ch*16384 + (b*128+d)*16;
  *(uint4*)hbuf     = *(const uint4*)(Hin+gidx);
  *(uint4*)(hbuf+8) = *(const uint4*)(Hin+gidx+8);
  #pragma unroll
  for(int s=0;s<16;s++){ A[s] = -__expf(alog[d*16+s]); h[s] = b2f(hbuf[s]); }
  float Dd = Dp[d];
  float dtv[16], xiv[16], zsv[16];
  #pragma unroll
  for(int i=0;i<CHL;i++){
    dtv[i] = b2f(dt[(size_t)(pbase+i)*128 + d]);
    xiv[i] = b2f(xi[(size_t)(pbase+i)*128 + d]);
    zsv[i] = b2f(zs[(size_t)(pbase+i)*128 + d]);
  }
  __syncthreads();
  #pragma unroll
  for(int i=0;i<CHL;i++){
    float Bv[16], Cv[16];
    unpack16(*(const uint4*)(sbc + i*32),      *(const uint4*)(sbc + i*32 + 8),  Bv);
    unpack16(*(const uint4*)(sbc + i*32 + 16), *(const uint4*)(sbc + i*32 + 24), Cv);
    float u = dtv[i]*xiv[i];
    float acc = Dd*xiv[i];
    #pragma unroll
    for(int s=0;s<16;s++){
      float a = __expf(dtv[i]*A[s]);
      h[s] = a*h[s] + u*Bv[s];
      acc += h[s]*Cv[s];
    }
    sY[i*LDY + d] = f2b(acc * zsv[i]);
  }
  __syncthreads();
  int ln = tid & 63, wv = tid >> 6;
  int mrow = ln & 15, quad = ln >> 4;
  f4v acc2[2];
  acc2[0] = (f4v){0.f,0.f,0.f,0.f};
  acc2[1] = (f4v){0.f,0.f,0.f,0.f};
  #pragma unroll
  for(int kk=0; kk<128; kk+=32){
    s8v af = *(const s8v*)(sY + mrow*LDY + kk + quad*8);
    #pragma unroll
    for(int ns=0; ns<2; ns++){
      int n0 = wv*32 + ns*16;
      s8v bf = *(const s8v*)(sWo + (n0+mrow)*LDW + kk + quad*8);
      acc2[ns] = __builtin_amdgcn_mfma_f32_16x16x32_bf16(af, bf, acc2[ns], 0, 0, 0);
    }
  }
  #pragma unroll
  for(int ns=0; ns<2; ns++){
    int n = wv*32 + ns*16 + mrow;
    #pragma unroll
    for(int r=0;r<4;r++){
      int px = pbase + quad*4 + r;
      y[(size_t)px*64 + n] = f2b(acc2[ns][r] + b2f(x0[(size_t)px*64 + n]));
    }
  }
}

// ========== MFMA with fused LayerNorm on A (CIN=64) ==========
template<int COUT, int ACT>
__global__ __launch_bounds__(256) void k_mfma_ln(const u16* __restrict__ wT,
                     const u16* __restrict__ in, const float* __restrict__ g,
                     const float* __restrict__ bta, u16* __restrict__ outp){
  const int CIN = 64, LDA = 72, NS = COUT/16;
  __shared__ __align__(16) u16 sA[64*LDA];
  __shared__ __align__(16) u16 sW[COUT*LDA];
  int tid = threadIdx.x;
  int p0 = blockIdx.x * 64;
  int ln = tid & 63, wv = tid >> 6;
  int mrow = ln & 15, quad = ln >> 4;
  for(int idx=tid; idx<COUT*8; idx+=256){
    int n = idx>>3, c8 = (idx&7)*8;
    *(uint4*)(sW + n*LDA + c8) = *(const uint4*)(wT + n*64 + c8);
  }
  float gg = g[ln], bb = bta[ln];
  #pragma unroll
  for(int i=0;i<16;i++){
    int row = wv*16 + i;
    float v = b2f(in[(size_t)(p0+row)*64 + ln]);
    float s = v, sq = v*v;
    #pragma unroll
    for(int o=32;o>0;o>>=1){ s += __shfl_xor(s,o); sq += __shfl_xor(sq,o); }
    float m = s*(1.f/64.f);
    float var = sq*(1.f/64.f) - m*m;
    float r = rsqrtf(var + 1e-5f);
    sA[row*LDA + ln] = f2b((v-m)*r*gg + bb);
  }
  __syncthreads();
  f4v acc[NS];
  #pragma unroll
  for(int i=0;i<NS;i++) acc[i] = (f4v){0.f,0.f,0.f,0.f};
  const u16* aBase = sA + (wv*16 + mrow)*LDA + quad*8;
  const u16* wBase = sW + mrow*LDA + quad*8;
  #pragma unroll
  for(int kk=0; kk<CIN; kk+=32){
    s8v af = *(const s8v*)(aBase + kk);
    #pragma unroll
    for(int ns=0; ns<NS; ns++){
      s8v bf = *(const s8v*)(wBase + ns*16*LDA + kk);
      acc[ns] = __builtin_amdgcn_mfma_f32_16x16x32_bf16(af, bf, acc[ns], 0, 0, 0);
    }
  }
  int pr = p0 + wv*16 + quad*4;
  #pragma unroll
  for(int ns=0; ns<NS; ns++){
    int n = ns*16 + mrow;
    #pragma unroll
    for(int r=0;r<4;r++){
      float v = acc[ns][r];
      if(ACT==1) v = leaky02(v);
      outp[(size_t)(pr+r)*COUT + n] = f2b(v);
    }
  }
}

// ========== final MFMA: [NPIX,256] @ wf2t[64][256] + res, fp32 NCHW store ==========
__global__ __launch_bounds__(256) void k_mfma_fin(const u16* __restrict__ wT,
                     const u16* __restrict__ in, const u16* __restrict__ res,
                     float* __restrict__ outp){
  const int CIN=256, COUT=64, KCH=128, LDA=136, NS=4;
  __shared__ __align__(16) u16 sA[64*LDA];
  __shared__ __align__(16) u16 sW[COUT*LDA];
  int tid = threadIdx.x;
  int p0 = blockIdx.x * 64;
  int ln = tid & 63, wv = tid >> 6;
  int mrow = ln & 15, quad = ln >> 4;
  f4v acc[NS];
  #pragma unroll
  for(int i=0;i<NS;i++) acc[i] = (f4v){0.f,0.f,0.f,0.f};
  const u16* aBase = sA + (wv*16 + mrow)*LDA + quad*8;
  const u16* wBase = sW + mrow*LDA + quad*8;
  for(int k0=0; k0<CIN; k0+=KCH){
    if(k0) __syncthreads();
    for(int idx=tid; idx<COUT*16; idx+=256){
      int n = idx>>4, c8 = (idx&15)*8;
      *(uint4*)(sW + n*LDA + c8) = *(const uint4*)(wT + n*256 + k0 + c8);
    }
    for(int g=tid; g<64*16; g+=256){
      int row = g >> 4, c8 = (g & 15)*8;
      *(uint4*)(sA + row*LDA + c8) = *(const uint4*)(in + (size_t)(p0+row)*CIN + k0 + c8);
    }
    __syncthreads();
    #pragma unroll
    for(int kk=0; kk<KCH; kk+=32){
      s8v af = *(const s8v*)(aBase + kk);
      #pragma unroll
      for(int ns=0; ns<NS; ns++){
        s8v bf = *(const s8v*)(wBase + ns*16*LDA + kk);
        acc[ns] = __builtin_amdgcn_mfma_f32_16x16x32_bf16(af, bf, acc[ns], 0, 0, 0);
      }
    }
  }
  int pr = p0 + wv*16 + quad*4;
  int b = blockIdx.x >> 6;
  int hwr = ((blockIdx.x & 63) << 6) + wv*16 + quad*4;
  #pragma unroll
  for(int ns=0; ns<NS; ns++){
    int n = ns*16 + mrow;
    float4 v4;
    v4.x = acc[ns][0] + b2f(res[(size_t)(pr+0)*64 + n]);
    v4.y = acc[ns][1] + b2f(res[(size_t)(pr+1)*64 + n]);
    v4.z = acc[ns][2] + b2f(res[(size_t)(pr+2)*64 + n]);
    v4.w = acc[ns][3] + b2f(res[(size_t)(pr+3)*64 + n]);
    *(float4*)(outp + (size_t)b*C_*HW_ + (size_t)n*HW_ + hwr) = v4;
  }
}

// ---------------- depthwise 3x3 SAME, 4 channels per thread ----------------
template<int CN, int ACT>
__global__ void k_dw3(const u16* __restrict__ in, const float* __restrict__ wgt,
                      const u16* __restrict__ res1, const u16* __restrict__ res2,
                      u16* __restrict__ out){
  const int C4 = CN/4;
  int g = blockIdx.x*256 + threadIdx.x;
  int c4 = g % C4;
  int pix = g / C4;
  int w = pix & 63;
  int h = (pix >> 6) & 63;
  int b = pix >> 12;
  float a0=0.f, a1=0.f, a2=0.f, a3=0.f;
  #pragma unroll
  for(int kh=0;kh<3;kh++){
    int hh = h + kh - 1;
    if((unsigned)hh < 64u){
      #pragma unroll
      for(int kw=0;kw<3;kw++){
        int ww = w + kw - 1;
        if((unsigned)ww < 64u){
          ushort4 v = *(const ushort4*)(in + (size_t)((b*64+hh)*64 + ww)*CN + c4*4);
          float4 wv = *(const float4*)(wgt + (kh*3+kw)*CN + c4*4);
          a0 += b2f(v.x)*wv.x; a1 += b2f(v.y)*wv.y;
          a2 += b2f(v.z)*wv.z; a3 += b2f(v.w)*wv.w;
        }
      }
    }
  }
  if(ACT==1){ a0=leaky02(a0); a1=leaky02(a1); a2=leaky02(a2); a3=leaky02(a3); }
  else if(ACT==2){ a0=gelu_exact(a0); a1=gelu_exact(a1); a2=gelu_exact(a2); a3=gelu_exact(a3); }
  size_t ob = (size_t)pix*CN + c4*4;
  if(res1){ ushort4 r = *(const ushort4*)(res1 + ob);
            a0+=b2f(r.x); a1+=b2f(r.y); a2+=b2f(r.z); a3+=b2f(r.w); }
  if(res2){ ushort4 r = *(const ushort4*)(res2 + ob);
            a0+=b2f(r.x); a1+=b2f(r.y); a2+=b2f(r.z); a3+=b2f(r.w); }
  ushort4 o; o.x=f2b(a0); o.y=f2b(a1); o.z=f2b(a2); o.w=f2b(a3);
  *(ushort4*)(out + ob) = o;
}

extern "C" void kernel_launch(void* const* d_in, const int* in_sizes, int n_in,
                              void* d_out, int out_size, void* d_ws, size_t ws_size,
                              hipStream_t stream) {
  const float* x        = (const float*)d_in[0];
  const float* ln1_g    = (const float*)d_in[1];
  const float* ln1_b    = (const float*)d_in[2];
  const float* vin_w1   = (const float*)d_in[3];
  const float* vin_dw   = (const float*)d_in[4];
  const float* vin_w2   = (const float*)d_in[5];
  const float* vout_dw1 = (const float*)d_in[6];
  const float* vout_dw2 = (const float*)d_in[7];
  const float* ssm_in_w = (const float*)d_in[8];
  const float* ssm_cw   = (const float*)d_in[9];
  const float* ssm_cb   = (const float*)d_in[10];
  const float* ssm_xprj = (const float*)d_in[11];
  const float* ssm_dtw  = (const float*)d_in[12];
  const float* ssm_dtb  = (const float*)d_in[13];
  const float* ssm_Alog = (const float*)d_in[14];
  const float* ssm_D    = (const float*)d_in[15];
  const float* ssm_outw = (const float*)d_in[16];
  const float* ln2_g    = (const float*)d_in[17];
  const float* ln2_b    = (const float*)d_in[18];
  const float* ff_w1    = (const float*)d_in[19];
  const float* ff_dw    = (const float*)d_in[20];
  const float* ff_w2    = (const float*)d_in[21];
  float* out = (float*)d_out;

  // ---- bf16 arena, lifetime-packed (units: bf16 elements) ----
  const size_t M = 1u<<20;
  u16* U   = (u16*)d_ws;
  u16* xT  = U;              // [0,2M)
  u16* tA  = U + 2*M;        // [2M,4M)   Hin during scan
  u16* tB  = U + 4*M;        // [4M,6M)
  u16* x0  = U + 6*M;        // [6M,8M)   x0, later xR
  u16* xi  = U + 8*M;        // [8M,12M)
  u16* zs  = U + 12*M;       // [12M,16M)
  u16* xz  = U + 16*M;       // [16M,24M) Pb/Qb; y; t1
  u16* dtb = U + 24*M;       // [24M,28M) dt; t2
  u16* bc  = U + 28*M;       // [28M,29M)
  u16* Pb  = U + 16*M;       // [16M,20M)
  u16* Qb  = U + 20*M;       // [20M,24M)
  u16* Hin = tA;             // [2M,6M)
  u16* y   = U + 16*M;       // [16M,18M)
  u16* t2  = dtb;            // [24M,32M)
  // pre-transposed bf16 weights:
  u16* wv1  = U + 33*M;
  u16* wv2  = wv1 + 4096;
  u16* wsi  = wv2 + 4096;
  u16* wdb  = wsi + 16384;
  u16* wout = wdb + 20480;
  u16* wf1  = wout + 8192;
  u16* wf2t = wf1 + 16384;

  k_prep<<<80,256,0,stream>>>(vin_w1, vin_w2, ssm_in_w, ssm_xprj, ssm_dtw, ssm_outw,
                              ff_w1, ff_w2, wv1, wv2, wsi, wdb, wout, wf1, wf2t);

  // --- vision in path (dw3+gelu+vin_w2 fused, 512 blocks) ---
  k_trans_ln_mm<<<512,256,0,stream>>>(x, ln1_g, ln1_b, wv1, xT, tB);
  k_dw3mm<<<512,256,0,stream>>>(tB, vin_dw, wv2, x0);

  // --- SSM (ssm_in + conv + dt/bc fused) ---
  k_ssm_dtbc<<<512,256,0,stream>>>(wsi, x0, ssm_cw, ssm_cb, wdb, ssm_dtb,
                                   xi, zs, dtb, bc);
  k_scan1<<<1024,256,0,stream>>>(dtb, xi, bc, ssm_Alog, Pb, Qb);
  k_scan2<<<128,64,0,stream>>>(Pb, Qb, Hin);
  k_scan3_mm<<<2048,128,0,stream>>>(dtb, xi, bc, zs, ssm_Alog, ssm_D, Hin, wout, x0, y);

  // --- vision out path:  xR = dw2(gelu(dw1(y))) + y + xT ---
  k_dw3<64,2><<<2048,256,0,stream>>>(y, vout_dw1, nullptr, nullptr, tA);
  k_dw3<64,0><<<2048,256,0,stream>>>(tA, vout_dw2, y, xT, x0);   // x0 now = xR

  // --- FFN ---
  k_mfma_ln<256,1><<<512,256,0,stream>>>(wf1, x0, ln2_g, ln2_b, xz);  // t1
  k_dw3<256,1><<<8192,256,0,stream>>>(xz, ff_dw, nullptr, nullptr, t2);
  k_mfma_fin<<<512,256,0,stream>>>(wf2t, t2, x0, out);
}